// Round 3
// baseline (301.508 us; speedup 1.0000x reference)
//
#include <hip/hip_runtime.h>
#include <cmath>

#define B_ 8
#define N_ 4096
#define D_ 512
#define M_ 512
#define EPS_ 1e-5f
#define DT_ 0.25f

typedef unsigned short u16;
typedef unsigned int u32;
typedef __attribute__((ext_vector_type(8))) u16 u16x8;
typedef __attribute__((ext_vector_type(8))) short bf16x8;
typedef __attribute__((ext_vector_type(4))) float f32x4;

__device__ __forceinline__ u16 f2bf(float f) {
    u32 u = __builtin_bit_cast(u32, f);
    u32 r = u + 0x7fffu + ((u >> 16) & 1u);   // round-to-nearest-even
    return (u16)(r >> 16);
}
__device__ __forceinline__ float bf2f(u16 h) {
    return __builtin_bit_cast(float, (u32)h << 16);
}

// ---------------------------------------------------------------------------
// Transpose + fp32->bf16: src [Z][R][C] -> dst [Z][C][R]
// ---------------------------------------------------------------------------
__global__ __launch_bounds__(256)
void k_prep_T(const float* __restrict__ src, u16* __restrict__ dst, int R, int C)
{
    __shared__ float tile[64][65];
    const int t = threadIdx.x;
    const int c0 = blockIdx.x * 64;
    const int r0 = blockIdx.y * 64;
    const int z  = blockIdx.z;
    const float* s = src + (size_t)z * R * C;
    u16* d = dst + (size_t)z * R * C;
    const int rl = t >> 4, cc = (t & 15) * 4;
#pragma unroll
    for (int i = 0; i < 4; ++i) {
        float4 v = *reinterpret_cast<const float4*>(s + (size_t)(r0 + rl + i * 16) * C + c0 + cc);
        tile[rl + i * 16][cc + 0] = v.x;
        tile[rl + i * 16][cc + 1] = v.y;
        tile[rl + i * 16][cc + 2] = v.z;
        tile[rl + i * 16][cc + 3] = v.w;
    }
    __syncthreads();
#pragma unroll
    for (int i = 0; i < 2; ++i) {
        int q = t + i * 256;
        int cl = q >> 3, rc = (q & 7) * 8;
        u16x8 o;
#pragma unroll
        for (int j = 0; j < 8; ++j) o[j] = f2bf(tile[rc + j][cl]);
        *reinterpret_cast<u16x8*>(d + (size_t)(c0 + cl) * R + r0 + rc) = o;
    }
}

// ---------------------------------------------------------------------------
// Projection: field[b] += kern[M,Nchunk] @ x[Nchunk,D] via bf16 MFMA.
// 128x128 tile, 8-way K-split over n, atomicAdd accumulate into fp32 field.
// grid (M/128, D/128, B*8), 512 thr (8 waves 2x4).
// ---------------------------------------------------------------------------
__global__ __launch_bounds__(512)
void k_project(const float* __restrict__ pos, const float* __restrict__ gp,
               const float* __restrict__ log_sigma, const u16* __restrict__ xT,
               float* __restrict__ field)
{
    __shared__ u16 As[128][72];   // kern [m][n]
    __shared__ u16 Bs[128][72];   // xT   [d][n]
    __shared__ float gs[128];
    const int t = threadIdx.x;
    const int m0 = blockIdx.x * 128, d0 = blockIdx.y * 128;
    const int z = blockIdx.z;
    const int b = z >> 3, kc = z & 7;              // 8 K-chunks of 512 n
    const int l = t & 63, wid = t >> 6;
    const int wm = wid >> 2, wn = wid & 3;

    if (t < 128) gs[t] = gp[(size_t)b * M_ + m0 + t];
    const float sigma = __expf(log_sigma[0]);
    const float ninv2s2 = -0.5f / (sigma * sigma);
    const float* pb = pos + (size_t)b * N_ + kc * 512;
    const u16* xb = xT + ((size_t)b * D_ + d0) * N_ + kc * 512;

    f32x4 acc[4][2];
#pragma unroll
    for (int i = 0; i < 4; ++i)
#pragma unroll
        for (int j = 0; j < 2; ++j) acc[i][j] = (f32x4){0.f, 0.f, 0.f, 0.f};

    const int srow = t >> 2, ssub = (t & 3) * 16;
    __syncthreads();   // gs visible

    for (int it = 0; it < 8; ++it) {
        const int n0 = it * 64;
        __syncthreads();   // protect previous tile reads
        {   // stage kern: thread does 16 exps for row srow, cols ssub..+15
            const float gm = gs[srow];
            float4 p0 = *reinterpret_cast<const float4*>(pb + n0 + ssub);
            float4 p1 = *reinterpret_cast<const float4*>(pb + n0 + ssub + 4);
            float4 p2 = *reinterpret_cast<const float4*>(pb + n0 + ssub + 8);
            float4 p3 = *reinterpret_cast<const float4*>(pb + n0 + ssub + 12);
            float dv[16] = {gm-p0.x, gm-p0.y, gm-p0.z, gm-p0.w,
                            gm-p1.x, gm-p1.y, gm-p1.z, gm-p1.w,
                            gm-p2.x, gm-p2.y, gm-p2.z, gm-p2.w,
                            gm-p3.x, gm-p3.y, gm-p3.z, gm-p3.w};
            u16x8 k0, k1;
#pragma unroll
            for (int j = 0; j < 8; ++j) k0[j] = f2bf(__expf(dv[j] * dv[j] * ninv2s2));
#pragma unroll
            for (int j = 0; j < 8; ++j) k1[j] = f2bf(__expf(dv[j+8] * dv[j+8] * ninv2s2));
            *reinterpret_cast<u16x8*>(&As[srow][ssub])     = k0;
            *reinterpret_cast<u16x8*>(&As[srow][ssub + 8]) = k1;
        }
        {   // stage xT tile
            u16x8 v0 = *reinterpret_cast<const u16x8*>(xb + (size_t)srow * N_ + n0 + ssub);
            u16x8 v1 = *reinterpret_cast<const u16x8*>(xb + (size_t)srow * N_ + n0 + ssub + 8);
            *reinterpret_cast<u16x8*>(&Bs[srow][ssub])     = v0;
            *reinterpret_cast<u16x8*>(&Bs[srow][ssub + 8]) = v1;
        }
        __syncthreads();
#pragma unroll
        for (int kk = 0; kk < 64; kk += 32) {
            const int ko = kk + (l >> 4) * 8;
            bf16x8 bfr[2];
#pragma unroll
            for (int nf = 0; nf < 2; ++nf)
                bfr[nf] = *reinterpret_cast<const bf16x8*>(&Bs[wn * 32 + nf * 16 + (l & 15)][ko]);
#pragma unroll
            for (int mf = 0; mf < 4; ++mf) {
                bf16x8 a = *reinterpret_cast<const bf16x8*>(&As[wm * 64 + mf * 16 + (l & 15)][ko]);
                acc[mf][0] = __builtin_amdgcn_mfma_f32_16x16x32_bf16(a, bfr[0], acc[mf][0], 0, 0, 0);
                acc[mf][1] = __builtin_amdgcn_mfma_f32_16x16x32_bf16(a, bfr[1], acc[mf][1], 0, 0, 0);
            }
        }
    }

    float* fb = field + (size_t)b * M_ * D_;
#pragma unroll
    for (int mf = 0; mf < 4; ++mf)
#pragma unroll
        for (int nf = 0; nf < 2; ++nf)
#pragma unroll
            for (int r = 0; r < 4; ++r) {
                const int m = m0 + wm * 64 + mf * 16 + (l >> 4) * 4 + r;
                const int d = d0 + wn * 32 + nf * 16 + (l & 15);
                unsafeAtomicAdd(fb + (size_t)m * D_ + d, acc[mf][nf][r]);
            }
}

// ---------------------------------------------------------------------------
// Diffusion step: fout = fin + dt*(alpha*lap + tanh(fin @ Wi + bi))
// ---------------------------------------------------------------------------
__global__ __launch_bounds__(256)
void k_diffuse(const float* __restrict__ fin, const u16* __restrict__ WiT,
               const float* __restrict__ bi, const float* __restrict__ alpha_p,
               float* __restrict__ fout)
{
    __shared__ u16 fs[16][520];
    const int t = threadIdx.x;
    const int m0 = blockIdx.x * 16;
    const int cb0 = blockIdx.y * 256;
    const int b = blockIdx.z;
    const int l = t & 63, wn = t >> 6;
    const float* fb = fin + (size_t)b * M_ * D_;

    {
        const int row = t >> 4, ch = (t & 15) * 32;
        const float* src = fb + (size_t)(m0 + row) * D_ + ch;
#pragma unroll
        for (int j = 0; j < 4; ++j) {
            float4 v0 = *reinterpret_cast<const float4*>(src + j * 8);
            float4 v1 = *reinterpret_cast<const float4*>(src + j * 8 + 4);
            u16x8 o;
            o[0] = f2bf(v0.x); o[1] = f2bf(v0.y); o[2] = f2bf(v0.z); o[3] = f2bf(v0.w);
            o[4] = f2bf(v1.x); o[5] = f2bf(v1.y); o[6] = f2bf(v1.z); o[7] = f2bf(v1.w);
            *reinterpret_cast<u16x8*>(&fs[row][ch + j * 8]) = o;
        }
    }
    __syncthreads();

    f32x4 acc[4];
#pragma unroll
    for (int i = 0; i < 4; ++i) acc[i] = (f32x4){0.f, 0.f, 0.f, 0.f};
    const int colb = cb0 + wn * 64;

    for (int kk = 0; kk < D_; kk += 32) {
        const int ko = kk + (l >> 4) * 8;
        bf16x8 a = *reinterpret_cast<const bf16x8*>(&fs[l & 15][ko]);
#pragma unroll
        for (int nf = 0; nf < 4; ++nf) {
            bf16x8 w = *reinterpret_cast<const bf16x8*>(WiT + (size_t)(colb + nf * 16 + (l & 15)) * D_ + ko);
            acc[nf] = __builtin_amdgcn_mfma_f32_16x16x32_bf16(a, w, acc[nf], 0, 0, 0);
        }
    }

    const float al = alpha_p[0];
    float* fob = fout + (size_t)b * M_ * D_;
#pragma unroll
    for (int nf = 0; nf < 4; ++nf) {
        const int col = colb + nf * 16 + (l & 15);
        const float bic = bi[col];
#pragma unroll
        for (int r = 0; r < 4; ++r) {
            const int m = m0 + (l >> 4) * 4 + r;
            const int mu_ = m > 0 ? m - 1 : 0;
            const int md = m < M_ - 1 ? m + 1 : M_ - 1;
            float fc = fb[(size_t)m * D_ + col];
            float fl_ = fb[(size_t)mu_ * D_ + col];
            float fr_ = fb[(size_t)md * D_ + col];
            float lap = fl_ + fr_ - 2.f * fc;
            fob[(size_t)m * D_ + col] = fc + DT_ * (al * lap + tanhf(acc[nf][r] + bic));
        }
    }
}

// ---------------------------------------------------------------------------
// Tail part 1: enh = LN1(lerp(field) + x) -> bf16.  Zero LDS, one wave/row.
// grid (N/4, B), 256 thr.
// ---------------------------------------------------------------------------
__global__ __launch_bounds__(256)
void k_enh(const float* __restrict__ x, const float* __restrict__ pos,
           const float* __restrict__ field, const float* __restrict__ g1,
           const float* __restrict__ b1, u16* __restrict__ enh)
{
    const int t = threadIdx.x;
    const int wid = t >> 6, l = t & 63;
    const int n = blockIdx.x * 4 + wid;
    const int b = blockIdx.y;
    const int c = l * 8;

    const float* xr = x + ((size_t)b * N_ + n) * D_ + c;
    float4 xa = *reinterpret_cast<const float4*>(xr);
    float4 xb = *reinterpret_cast<const float4*>(xr + 4);
    const float p = pos[(size_t)b * N_ + n];
    float u = p * (float)(M_ - 1);
    int i0 = (int)floorf(u);
    i0 = i0 < 0 ? 0 : (i0 > M_ - 2 ? M_ - 2 : i0);
    const float w = u - (float)i0;
    const float* fp0 = field + ((size_t)b * M_ + i0) * D_ + c;
    float4 f0a = *reinterpret_cast<const float4*>(fp0);
    float4 f0b = *reinterpret_cast<const float4*>(fp0 + 4);
    float4 f1a = *reinterpret_cast<const float4*>(fp0 + D_);
    float4 f1b = *reinterpret_cast<const float4*>(fp0 + D_ + 4);

    float s[8];
    s[0] = f0a.x + w * (f1a.x - f0a.x) + xa.x;
    s[1] = f0a.y + w * (f1a.y - f0a.y) + xa.y;
    s[2] = f0a.z + w * (f1a.z - f0a.z) + xa.z;
    s[3] = f0a.w + w * (f1a.w - f0a.w) + xa.w;
    s[4] = f0b.x + w * (f1b.x - f0b.x) + xb.x;
    s[5] = f0b.y + w * (f1b.y - f0b.y) + xb.y;
    s[6] = f0b.z + w * (f1b.z - f0b.z) + xb.z;
    s[7] = f0b.w + w * (f1b.w - f0b.w) + xb.w;

    float sum = 0.f, ss = 0.f;
#pragma unroll
    for (int j = 0; j < 8; ++j) { sum += s[j]; ss += s[j] * s[j]; }
#pragma unroll
    for (int off = 1; off <= 32; off <<= 1) {
        sum += __shfl_xor(sum, off);
        ss  += __shfl_xor(ss, off);
    }
    const float mu = sum * (1.f / 512.f);
    const float rs = rsqrtf(ss * (1.f / 512.f) - mu * mu + EPS_);

    float4 ga = *reinterpret_cast<const float4*>(g1 + c);
    float4 gb = *reinterpret_cast<const float4*>(g1 + c + 4);
    float4 ba = *reinterpret_cast<const float4*>(b1 + c);
    float4 bb = *reinterpret_cast<const float4*>(b1 + c + 4);
    u16x8 e;
    e[0] = f2bf((s[0] - mu) * rs * ga.x + ba.x);
    e[1] = f2bf((s[1] - mu) * rs * ga.y + ba.y);
    e[2] = f2bf((s[2] - mu) * rs * ga.z + ba.z);
    e[3] = f2bf((s[3] - mu) * rs * ga.w + ba.w);
    e[4] = f2bf((s[4] - mu) * rs * gb.x + bb.x);
    e[5] = f2bf((s[5] - mu) * rs * gb.y + bb.y);
    e[6] = f2bf((s[6] - mu) * rs * gb.z + bb.z);
    e[7] = f2bf((s[7] - mu) * rs * gb.w + bb.w);
    *reinterpret_cast<u16x8*>(enh + ((size_t)b * N_ + n) * D_ + c) = e;
}

// ---------------------------------------------------------------------------
// Tail part 2: out = LN2(enh @ WoT + bo + enh).  enh tile bulk-loaded into
// XOR-swizzled LDS (conflict-free b128), barrier-free K-loop, W from L2.
// grid (B*N/64), 512 thr (8 waves 2x4).
// ---------------------------------------------------------------------------
__device__ __forceinline__ int swz(int row, int col) {   // u16 index in [64][512]
    return row * 512 + (col ^ ((row & 7) << 3));
}

__global__ __launch_bounds__(512)
void k_gemm_ln(const u16* __restrict__ enh, const u16* __restrict__ WoT,
               const float* __restrict__ bo, const float* __restrict__ g2,
               const float* __restrict__ b2, float* __restrict__ out)
{
    __shared__ u16 As[64 * 512];     // 64 KB, XOR-swizzled
    __shared__ float red[64][4][2];
    const int t = threadIdx.x;
    const int r0 = blockIdx.x * 64;  // row in flattened [B*N][D]
    const int l = t & 63, wid = t >> 6;
    const int wm = wid >> 2, wn = wid & 3;

    // ---- bulk stage: 8 rows x full width per thread-slice, coalesced ----
    {
        const int rowb = t >> 6, colb = (t & 63) * 8;
#pragma unroll
        for (int j = 0; j < 8; ++j) {
            const int row = rowb + j * 8;
            u16x8 v = *reinterpret_cast<const u16x8*>(enh + (size_t)(r0 + row) * D_ + colb);
            *reinterpret_cast<u16x8*>(&As[swz(row, colb)]) = v;
        }
    }
    __syncthreads();

    // ---- GEMM: barrier-free K-loop ----
    f32x4 acc[2][8];
#pragma unroll
    for (int i = 0; i < 2; ++i)
#pragma unroll
        for (int j = 0; j < 8; ++j) acc[i][j] = (f32x4){0.f, 0.f, 0.f, 0.f};

    for (int kk = 0; kk < D_; kk += 32) {
        const int ko = kk + (l >> 4) * 8;
        bf16x8 a0 = *reinterpret_cast<const bf16x8*>(&As[swz(wm * 32 + (l & 15), ko)]);
        bf16x8 a1 = *reinterpret_cast<const bf16x8*>(&As[swz(wm * 32 + 16 + (l & 15), ko)]);
#pragma unroll
        for (int nf = 0; nf < 8; ++nf) {
            const int col = wn * 128 + nf * 16 + (l & 15);
            bf16x8 bw = *reinterpret_cast<const bf16x8*>(WoT + (size_t)col * D_ + ko);
            acc[0][nf] = __builtin_amdgcn_mfma_f32_16x16x32_bf16(a0, bw, acc[0][nf], 0, 0, 0);
            acc[1][nf] = __builtin_amdgcn_mfma_f32_16x16x32_bf16(a1, bw, acc[1][nf], 0, 0, 0);
        }
    }

    // ---- bias + residual + partial LN2 sums ----
    float psum[2][4], pss[2][4];
#pragma unroll
    for (int mf = 0; mf < 2; ++mf)
#pragma unroll
        for (int r = 0; r < 4; ++r) { psum[mf][r] = 0.f; pss[mf][r] = 0.f; }

#pragma unroll
    for (int nf = 0; nf < 8; ++nf) {
        const int col = wn * 128 + nf * 16 + (l & 15);
        const float boc = bo[col];
#pragma unroll
        for (int mf = 0; mf < 2; ++mf)
#pragma unroll
            for (int r = 0; r < 4; ++r) {
                const int row = wm * 32 + mf * 16 + (l >> 4) * 4 + r;
                float v = acc[mf][nf][r] + boc + bf2f(As[swz(row, col)]);
                acc[mf][nf][r] = v;
                psum[mf][r] += v;
                pss[mf][r]  += v * v;
            }
    }
#pragma unroll
    for (int off = 1; off <= 8; off <<= 1) {
#pragma unroll
        for (int mf = 0; mf < 2; ++mf)
#pragma unroll
            for (int r = 0; r < 4; ++r) {
                psum[mf][r] += __shfl_xor(psum[mf][r], off);
                pss[mf][r]  += __shfl_xor(pss[mf][r], off);
            }
    }
    if ((l & 15) == 0) {
#pragma unroll
        for (int mf = 0; mf < 2; ++mf)
#pragma unroll
            for (int r = 0; r < 4; ++r) {
                const int row = wm * 32 + mf * 16 + (l >> 4) * 4 + r;
                red[row][wn][0] = psum[mf][r];
                red[row][wn][1] = pss[mf][r];
            }
    }
    __syncthreads();

    // ---- LN2 + store ----
#pragma unroll
    for (int mf = 0; mf < 2; ++mf)
#pragma unroll
        for (int r = 0; r < 4; ++r) {
            const int row = wm * 32 + mf * 16 + (l >> 4) * 4 + r;
            float s  = red[row][0][0] + red[row][1][0] + red[row][2][0] + red[row][3][0];
            float ss = red[row][0][1] + red[row][1][1] + red[row][2][1] + red[row][3][1];
            float mu = s * (1.f / 512.f);
            float rs = rsqrtf(ss * (1.f / 512.f) - mu * mu + EPS_);
#pragma unroll
            for (int nf = 0; nf < 8; ++nf) {
                const int col = wn * 128 + nf * 16 + (l & 15);
                out[(size_t)(r0 + row) * D_ + col] =
                    (acc[mf][nf][r] - mu) * rs * g2[col] + b2[col];
            }
        }
}

extern "C" void kernel_launch(void* const* d_in, const int* in_sizes, int n_in,
                              void* d_out, int out_size, void* d_ws, size_t ws_size,
                              hipStream_t stream) {
    (void)in_sizes; (void)n_in; (void)out_size; (void)ws_size;
    const float* x   = (const float*)d_in[0];
    const float* pos = (const float*)d_in[1];
    const float* gp  = (const float*)d_in[2];
    const float* ls  = (const float*)d_in[3];
    const float* al  = (const float*)d_in[4];
    const float* Wi  = (const float*)d_in[5];
    const float* bi  = (const float*)d_in[6];
    const float* g1  = (const float*)d_in[7];
    const float* b1  = (const float*)d_in[8];
    const float* Wo  = (const float*)d_in[9];
    const float* bo  = (const float*)d_in[10];
    const float* g2  = (const float*)d_in[11];
    const float* b2  = (const float*)d_in[12];
    float* out = (float*)d_out;

    float* f0 = (float*)d_ws;                              // 8 MB fp32 field
    float* f1 = f0 + (size_t)B_ * M_ * D_;                 // 8 MB ping-pong
    u16* xT  = (u16*)(f1 + (size_t)B_ * M_ * D_);          // 32 MB bf16 x^T
    u16* WiT = xT + (size_t)B_ * D_ * N_;                  // 512 KB
    u16* WoT = WiT + (size_t)D_ * D_;                      // 512 KB
    u16* enh = xT;                                         // alias: xT dead after project

    hipMemsetAsync(f0, 0, (size_t)B_ * M_ * D_ * sizeof(float), stream);
    k_prep_T<<<dim3(D_ / 64, N_ / 64, B_), 256, 0, stream>>>(x, xT, N_, D_);
    k_prep_T<<<dim3(D_ / 64, D_ / 64, 1), 256, 0, stream>>>(Wi, WiT, D_, D_);
    k_prep_T<<<dim3(D_ / 64, D_ / 64, 1), 256, 0, stream>>>(Wo, WoT, D_, D_);
    k_project<<<dim3(M_ / 128, D_ / 128, B_ * 8), 512, 0, stream>>>(pos, gp, ls, xT, f0);
    k_diffuse<<<dim3(M_ / 16, D_ / 256, B_), 256, 0, stream>>>(f0, WiT, bi, al, f1);
    k_diffuse<<<dim3(M_ / 16, D_ / 256, B_), 256, 0, stream>>>(f1, WiT, bi, al, f0);
    k_diffuse<<<dim3(M_ / 16, D_ / 256, B_), 256, 0, stream>>>(f0, WiT, bi, al, f1);
    k_diffuse<<<dim3(M_ / 16, D_ / 256, B_), 256, 0, stream>>>(f1, WiT, bi, al, f0);
    k_enh<<<dim3(N_ / 4, B_), 256, 0, stream>>>(x, pos, f0, g1, b1, enh);
    k_gemm_ln<<<dim3(B_ * N_ / 64), 512, 0, stream>>>(enh, WoT, bo, g2, b2, out);
}

// Round 4
// 301.250 us; speedup vs baseline: 1.0009x; 1.0009x over previous
//
#include <hip/hip_runtime.h>
#include <cmath>

#define B_ 8
#define N_ 4096
#define D_ 512
#define M_ 512
#define EPS_ 1e-5f
#define DT_ 0.25f

typedef unsigned short u16;
typedef unsigned int u32;
typedef __attribute__((ext_vector_type(8))) u16 u16x8;
typedef __attribute__((ext_vector_type(8))) short bf16x8;
typedef __attribute__((ext_vector_type(4))) float f32x4;

__device__ __forceinline__ u16 f2bf(float f) {
    u32 u = __builtin_bit_cast(u32, f);
    u32 r = u + 0x7fffu + ((u >> 16) & 1u);   // round-to-nearest-even
    return (u16)(r >> 16);
}
__device__ __forceinline__ float bf2f(u16 h) {
    return __builtin_bit_cast(float, (u32)h << 16);
}

// ---------------------------------------------------------------------------
// Transpose + fp32->bf16: src [Z][R][C] -> dst [Z][C][R]
// ---------------------------------------------------------------------------
__global__ __launch_bounds__(256)
void k_prep_T(const float* __restrict__ src, u16* __restrict__ dst, int R, int C)
{
    __shared__ float tile[64][65];
    const int t = threadIdx.x;
    const int c0 = blockIdx.x * 64;
    const int r0 = blockIdx.y * 64;
    const int z  = blockIdx.z;
    const float* s = src + (size_t)z * R * C;
    u16* d = dst + (size_t)z * R * C;
    const int rl = t >> 4, cc = (t & 15) * 4;
#pragma unroll
    for (int i = 0; i < 4; ++i) {
        float4 v = *reinterpret_cast<const float4*>(s + (size_t)(r0 + rl + i * 16) * C + c0 + cc);
        tile[rl + i * 16][cc + 0] = v.x;
        tile[rl + i * 16][cc + 1] = v.y;
        tile[rl + i * 16][cc + 2] = v.z;
        tile[rl + i * 16][cc + 3] = v.w;
    }
    __syncthreads();
#pragma unroll
    for (int i = 0; i < 2; ++i) {
        int q = t + i * 256;
        int cl = q >> 3, rc = (q & 7) * 8;
        u16x8 o;
#pragma unroll
        for (int j = 0; j < 8; ++j) o[j] = f2bf(tile[rc + j][cl]);
        *reinterpret_cast<u16x8*>(d + (size_t)(c0 + cl) * R + r0 + rc) = o;
    }
}

// ---------------------------------------------------------------------------
// Projection: field[b] += kern[M,Nchunk] @ x[Nchunk,D] via bf16 MFMA.
// 128x128 tile, 8-way K-split over n, atomicAdd accumulate into fp32 field.
// grid (M/128, D/128, B*8), 512 thr (8 waves 2x4).
// ---------------------------------------------------------------------------
__global__ __launch_bounds__(512)
void k_project(const float* __restrict__ pos, const float* __restrict__ gp,
               const float* __restrict__ log_sigma, const u16* __restrict__ xT,
               float* __restrict__ field)
{
    __shared__ u16 As[128][72];   // kern [m][n]
    __shared__ u16 Bs[128][72];   // xT   [d][n]
    __shared__ float gs[128];
    const int t = threadIdx.x;
    const int m0 = blockIdx.x * 128, d0 = blockIdx.y * 128;
    const int z = blockIdx.z;
    const int b = z >> 3, kc = z & 7;              // 8 K-chunks of 512 n
    const int l = t & 63, wid = t >> 6;
    const int wm = wid >> 2, wn = wid & 3;

    if (t < 128) gs[t] = gp[(size_t)b * M_ + m0 + t];
    const float sigma = __expf(log_sigma[0]);
    const float ninv2s2 = -0.5f / (sigma * sigma);
    const float* pb = pos + (size_t)b * N_ + kc * 512;
    const u16* xb = xT + ((size_t)b * D_ + d0) * N_ + kc * 512;

    f32x4 acc[4][2];
#pragma unroll
    for (int i = 0; i < 4; ++i)
#pragma unroll
        for (int j = 0; j < 2; ++j) acc[i][j] = (f32x4){0.f, 0.f, 0.f, 0.f};

    const int srow = t >> 2, ssub = (t & 3) * 16;
    __syncthreads();   // gs visible

    for (int it = 0; it < 8; ++it) {
        const int n0 = it * 64;
        __syncthreads();   // protect previous tile reads
        {   // stage kern: thread does 16 exps for row srow, cols ssub..+15
            const float gm = gs[srow];
            float4 p0 = *reinterpret_cast<const float4*>(pb + n0 + ssub);
            float4 p1 = *reinterpret_cast<const float4*>(pb + n0 + ssub + 4);
            float4 p2 = *reinterpret_cast<const float4*>(pb + n0 + ssub + 8);
            float4 p3 = *reinterpret_cast<const float4*>(pb + n0 + ssub + 12);
            float dv[16] = {gm-p0.x, gm-p0.y, gm-p0.z, gm-p0.w,
                            gm-p1.x, gm-p1.y, gm-p1.z, gm-p1.w,
                            gm-p2.x, gm-p2.y, gm-p2.z, gm-p2.w,
                            gm-p3.x, gm-p3.y, gm-p3.z, gm-p3.w};
            u16x8 k0, k1;
#pragma unroll
            for (int j = 0; j < 8; ++j) k0[j] = f2bf(__expf(dv[j] * dv[j] * ninv2s2));
#pragma unroll
            for (int j = 0; j < 8; ++j) k1[j] = f2bf(__expf(dv[j+8] * dv[j+8] * ninv2s2));
            *reinterpret_cast<u16x8*>(&As[srow][ssub])     = k0;
            *reinterpret_cast<u16x8*>(&As[srow][ssub + 8]) = k1;
        }
        {   // stage xT tile
            u16x8 v0 = *reinterpret_cast<const u16x8*>(xb + (size_t)srow * N_ + n0 + ssub);
            u16x8 v1 = *reinterpret_cast<const u16x8*>(xb + (size_t)srow * N_ + n0 + ssub + 8);
            *reinterpret_cast<u16x8*>(&Bs[srow][ssub])     = v0;
            *reinterpret_cast<u16x8*>(&Bs[srow][ssub + 8]) = v1;
        }
        __syncthreads();
#pragma unroll
        for (int kk = 0; kk < 64; kk += 32) {
            const int ko = kk + (l >> 4) * 8;
            bf16x8 bfr[2];
#pragma unroll
            for (int nf = 0; nf < 2; ++nf)
                bfr[nf] = *reinterpret_cast<const bf16x8*>(&Bs[wn * 32 + nf * 16 + (l & 15)][ko]);
#pragma unroll
            for (int mf = 0; mf < 4; ++mf) {
                bf16x8 a = *reinterpret_cast<const bf16x8*>(&As[wm * 64 + mf * 16 + (l & 15)][ko]);
                acc[mf][0] = __builtin_amdgcn_mfma_f32_16x16x32_bf16(a, bfr[0], acc[mf][0], 0, 0, 0);
                acc[mf][1] = __builtin_amdgcn_mfma_f32_16x16x32_bf16(a, bfr[1], acc[mf][1], 0, 0, 0);
            }
        }
    }

    float* fb = field + (size_t)b * M_ * D_;
#pragma unroll
    for (int mf = 0; mf < 4; ++mf)
#pragma unroll
        for (int nf = 0; nf < 2; ++nf)
#pragma unroll
            for (int r = 0; r < 4; ++r) {
                const int m = m0 + wm * 64 + mf * 16 + (l >> 4) * 4 + r;
                const int d = d0 + wn * 32 + nf * 16 + (l & 15);
                unsafeAtomicAdd(fb + (size_t)m * D_ + d, acc[mf][nf][r]);
            }
}

// ---------------------------------------------------------------------------
// Diffusion step: fout = fin + dt*(alpha*lap + tanh(fin @ Wi + bi))
// grid (M/16, D/256, B), 256 thr. GEMM -> Cs stage -> coalesced row pass.
// ---------------------------------------------------------------------------
__global__ __launch_bounds__(256)
void k_diffuse(const float* __restrict__ fin, const u16* __restrict__ WiT,
               const float* __restrict__ bi, const float* __restrict__ alpha_p,
               float* __restrict__ fout)
{
    __shared__ u16 fs[16][520];      // 16.6 KB bf16 field rows
    __shared__ float Cs[16][260];    // 16.6 KB fp32 gemm stage (260: conflict-free)
    const int t = threadIdx.x;
    const int m0 = blockIdx.x * 16;
    const int cb0 = blockIdx.y * 256;
    const int b = blockIdx.z;
    const int l = t & 63, wn = t >> 6;
    const float* fb = fin + (size_t)b * M_ * D_;

    {
        const int row = t >> 4, ch = (t & 15) * 32;
        const float* src = fb + (size_t)(m0 + row) * D_ + ch;
#pragma unroll
        for (int j = 0; j < 4; ++j) {
            float4 v0 = *reinterpret_cast<const float4*>(src + j * 8);
            float4 v1 = *reinterpret_cast<const float4*>(src + j * 8 + 4);
            u16x8 o;
            o[0] = f2bf(v0.x); o[1] = f2bf(v0.y); o[2] = f2bf(v0.z); o[3] = f2bf(v0.w);
            o[4] = f2bf(v1.x); o[5] = f2bf(v1.y); o[6] = f2bf(v1.z); o[7] = f2bf(v1.w);
            *reinterpret_cast<u16x8*>(&fs[row][ch + j * 8]) = o;
        }
    }
    __syncthreads();

    f32x4 acc[4];
#pragma unroll
    for (int i = 0; i < 4; ++i) acc[i] = (f32x4){0.f, 0.f, 0.f, 0.f};

    for (int kk = 0; kk < D_; kk += 32) {
        const int ko = kk + (l >> 4) * 8;
        bf16x8 a = *reinterpret_cast<const bf16x8*>(&fs[l & 15][ko]);
#pragma unroll
        for (int nf = 0; nf < 4; ++nf) {
            bf16x8 w = *reinterpret_cast<const bf16x8*>(
                WiT + (size_t)(cb0 + wn * 64 + nf * 16 + (l & 15)) * D_ + ko);
            acc[nf] = __builtin_amdgcn_mfma_f32_16x16x32_bf16(a, w, acc[nf], 0, 0, 0);
        }
    }

    // stage gemm+bias into Cs (scatter, conflict-free by 260 stride)
#pragma unroll
    for (int nf = 0; nf < 4; ++nf) {
        const int cl = wn * 64 + nf * 16 + (l & 15);
        const float bic = bi[cb0 + cl];
#pragma unroll
        for (int r = 0; r < 4; ++r)
            Cs[(l >> 4) * 4 + r][cl] = acc[nf][r] + bic;
    }
    __syncthreads();

    // row pass: wave wn owns rows wn*4..+3, fully vectorized
    const float al = alpha_p[0];
    float* fob = fout + (size_t)b * M_ * D_;
#pragma unroll
    for (int i = 0; i < 4; ++i) {
        const int row = wn * 4 + i;
        const int m = m0 + row;
        const int mu_ = m > 0 ? m - 1 : 0;
        const int md = m < M_ - 1 ? m + 1 : M_ - 1;
        const int cl = cb0 + l * 4;
        float4 g  = *reinterpret_cast<const float4*>(&Cs[row][l * 4]);
        float4 fc = *reinterpret_cast<const float4*>(fb + (size_t)m * D_ + cl);
        float4 fu = *reinterpret_cast<const float4*>(fb + (size_t)mu_ * D_ + cl);
        float4 fd = *reinterpret_cast<const float4*>(fb + (size_t)md * D_ + cl);
        float4 o;
        o.x = fc.x + DT_ * (al * (fu.x + fd.x - 2.f * fc.x) + tanhf(g.x));
        o.y = fc.y + DT_ * (al * (fu.y + fd.y - 2.f * fc.y) + tanhf(g.y));
        o.z = fc.z + DT_ * (al * (fu.z + fd.z - 2.f * fc.z) + tanhf(g.z));
        o.w = fc.w + DT_ * (al * (fu.w + fd.w - 2.f * fc.w) + tanhf(g.w));
        *reinterpret_cast<float4*>(fob + (size_t)m * D_ + cl) = o;
    }
}

// ---------------------------------------------------------------------------
// Tail part 1: enh = LN1(lerp(field) + x) -> bf16.  Zero LDS, one wave/row.
// grid (N/4, B), 256 thr.
// ---------------------------------------------------------------------------
__global__ __launch_bounds__(256)
void k_enh(const float* __restrict__ x, const float* __restrict__ pos,
           const float* __restrict__ field, const float* __restrict__ g1,
           const float* __restrict__ b1, u16* __restrict__ enh)
{
    const int t = threadIdx.x;
    const int wid = t >> 6, l = t & 63;
    const int n = blockIdx.x * 4 + wid;
    const int b = blockIdx.y;
    const int c = l * 8;

    const float* xr = x + ((size_t)b * N_ + n) * D_ + c;
    float4 xa = *reinterpret_cast<const float4*>(xr);
    float4 xb = *reinterpret_cast<const float4*>(xr + 4);
    const float p = pos[(size_t)b * N_ + n];
    float u = p * (float)(M_ - 1);
    int i0 = (int)floorf(u);
    i0 = i0 < 0 ? 0 : (i0 > M_ - 2 ? M_ - 2 : i0);
    const float w = u - (float)i0;
    const float* fp0 = field + ((size_t)b * M_ + i0) * D_ + c;
    float4 f0a = *reinterpret_cast<const float4*>(fp0);
    float4 f0b = *reinterpret_cast<const float4*>(fp0 + 4);
    float4 f1a = *reinterpret_cast<const float4*>(fp0 + D_);
    float4 f1b = *reinterpret_cast<const float4*>(fp0 + D_ + 4);

    float s[8];
    s[0] = f0a.x + w * (f1a.x - f0a.x) + xa.x;
    s[1] = f0a.y + w * (f1a.y - f0a.y) + xa.y;
    s[2] = f0a.z + w * (f1a.z - f0a.z) + xa.z;
    s[3] = f0a.w + w * (f1a.w - f0a.w) + xa.w;
    s[4] = f0b.x + w * (f1b.x - f0b.x) + xb.x;
    s[5] = f0b.y + w * (f1b.y - f0b.y) + xb.y;
    s[6] = f0b.z + w * (f1b.z - f0b.z) + xb.z;
    s[7] = f0b.w + w * (f1b.w - f0b.w) + xb.w;

    float sum = 0.f, ss = 0.f;
#pragma unroll
    for (int j = 0; j < 8; ++j) { sum += s[j]; ss += s[j] * s[j]; }
#pragma unroll
    for (int off = 1; off <= 32; off <<= 1) {
        sum += __shfl_xor(sum, off);
        ss  += __shfl_xor(ss, off);
    }
    const float mu = sum * (1.f / 512.f);
    const float rs = rsqrtf(ss * (1.f / 512.f) - mu * mu + EPS_);

    float4 ga = *reinterpret_cast<const float4*>(g1 + c);
    float4 gb = *reinterpret_cast<const float4*>(g1 + c + 4);
    float4 ba = *reinterpret_cast<const float4*>(b1 + c);
    float4 bb = *reinterpret_cast<const float4*>(b1 + c + 4);
    u16x8 e;
    e[0] = f2bf((s[0] - mu) * rs * ga.x + ba.x);
    e[1] = f2bf((s[1] - mu) * rs * ga.y + ba.y);
    e[2] = f2bf((s[2] - mu) * rs * ga.z + ba.z);
    e[3] = f2bf((s[3] - mu) * rs * ga.w + ba.w);
    e[4] = f2bf((s[4] - mu) * rs * gb.x + bb.x);
    e[5] = f2bf((s[5] - mu) * rs * gb.y + bb.y);
    e[6] = f2bf((s[6] - mu) * rs * gb.z + bb.z);
    e[7] = f2bf((s[7] - mu) * rs * gb.w + bb.w);
    *reinterpret_cast<u16x8*>(enh + ((size_t)b * N_ + n) * D_ + c) = e;
}

// ---------------------------------------------------------------------------
// Tail part 2: out = LN2(enh @ WoT + bo + enh).
// A-frags + residual read directly from global enh (L2/L3). LDS = fp32 C-stage
// Cs[32][516] (66KB dyn, conflict-free both ways). Two epilogue passes (mf).
// grid (B*N/64), 512 thr (8 waves 2x4).
// ---------------------------------------------------------------------------
__global__ __launch_bounds__(512)
void k_gemm_ln(const u16* __restrict__ enh, const u16* __restrict__ WoT,
               const float* __restrict__ bo, const float* __restrict__ g2,
               const float* __restrict__ b2, float* __restrict__ out)
{
    extern __shared__ float Cs[];    // [32][516]
    const int t = threadIdx.x;
    const int r0 = blockIdx.x * 64;  // row in flattened [B*N][D]
    const int l = t & 63, wid = t >> 6;
    const int wm = wid >> 2, wn = wid & 3;

    f32x4 acc[2][8];
#pragma unroll
    for (int i = 0; i < 2; ++i)
#pragma unroll
        for (int j = 0; j < 8; ++j) acc[i][j] = (f32x4){0.f, 0.f, 0.f, 0.f};

    const size_t arow0 = (size_t)(r0 + wm * 32 + (l & 15)) * D_;
    const size_t arow1 = arow0 + (size_t)16 * D_;

    for (int kk = 0; kk < D_; kk += 32) {
        const int ko = kk + (l >> 4) * 8;
        bf16x8 a0 = *reinterpret_cast<const bf16x8*>(enh + arow0 + ko);
        bf16x8 a1 = *reinterpret_cast<const bf16x8*>(enh + arow1 + ko);
#pragma unroll
        for (int nf = 0; nf < 8; ++nf) {
            const int col = wn * 128 + nf * 16 + (l & 15);
            bf16x8 bw = *reinterpret_cast<const bf16x8*>(WoT + (size_t)col * D_ + ko);
            acc[0][nf] = __builtin_amdgcn_mfma_f32_16x16x32_bf16(a0, bw, acc[0][nf], 0, 0, 0);
            acc[1][nf] = __builtin_amdgcn_mfma_f32_16x16x32_bf16(a1, bw, acc[1][nf], 0, 0, 0);
        }
    }

#pragma unroll
    for (int mf = 0; mf < 2; ++mf) {
        __syncthreads();   // pass separation (protects Cs reuse)
        // scatter acc + bias into Cs; localrow = wm*16 + (l>>4)*4 + r
#pragma unroll
        for (int nf = 0; nf < 8; ++nf) {
            const int col = wn * 128 + nf * 16 + (l & 15);
            const float boc = bo[col];
#pragma unroll
            for (int r = 0; r < 4; ++r)
                Cs[(wm * 16 + (l >> 4) * 4 + r) * 516 + col] = acc[mf][nf][r] + boc;
        }
        __syncthreads();
        // row pass: wave wid owns localrows wid*4..+3
#pragma unroll
        for (int i = 0; i < 4; ++i) {
            const int lr = wid * 4 + i;
            const int grow = r0 + (lr >> 4) * 32 + mf * 16 + (lr & 15);
            float4 fa = *reinterpret_cast<const float4*>(&Cs[lr * 516 + l * 8]);
            float4 fb4 = *reinterpret_cast<const float4*>(&Cs[lr * 516 + l * 8 + 4]);
            u16x8 e = *reinterpret_cast<const u16x8*>(enh + (size_t)grow * D_ + l * 8);
            float v[8];
            v[0] = fa.x + bf2f(e[0]); v[1] = fa.y + bf2f(e[1]);
            v[2] = fa.z + bf2f(e[2]); v[3] = fa.w + bf2f(e[3]);
            v[4] = fb4.x + bf2f(e[4]); v[5] = fb4.y + bf2f(e[5]);
            v[6] = fb4.z + bf2f(e[6]); v[7] = fb4.w + bf2f(e[7]);

            float sum = 0.f, ss = 0.f;
#pragma unroll
            for (int j = 0; j < 8; ++j) { sum += v[j]; ss += v[j] * v[j]; }
#pragma unroll
            for (int off = 1; off <= 32; off <<= 1) {
                sum += __shfl_xor(sum, off);
                ss  += __shfl_xor(ss, off);
            }
            const float mu = sum * (1.f / 512.f);
            const float rs = rsqrtf(ss * (1.f / 512.f) - mu * mu + EPS_);

            float4 ga = *reinterpret_cast<const float4*>(g2 + l * 8);
            float4 gb = *reinterpret_cast<const float4*>(g2 + l * 8 + 4);
            float4 ba = *reinterpret_cast<const float4*>(b2 + l * 8);
            float4 bb = *reinterpret_cast<const float4*>(b2 + l * 8 + 4);
            float4 oa, ob;
            oa.x = (v[0] - mu) * rs * ga.x + ba.x;
            oa.y = (v[1] - mu) * rs * ga.y + ba.y;
            oa.z = (v[2] - mu) * rs * ga.z + ba.z;
            oa.w = (v[3] - mu) * rs * ga.w + ba.w;
            ob.x = (v[4] - mu) * rs * gb.x + bb.x;
            ob.y = (v[5] - mu) * rs * gb.y + bb.y;
            ob.z = (v[6] - mu) * rs * gb.z + bb.z;
            ob.w = (v[7] - mu) * rs * gb.w + bb.w;
            float* orow = out + (size_t)grow * D_ + l * 8;
            *reinterpret_cast<float4*>(orow)     = oa;
            *reinterpret_cast<float4*>(orow + 4) = ob;
        }
    }
}

extern "C" void kernel_launch(void* const* d_in, const int* in_sizes, int n_in,
                              void* d_out, int out_size, void* d_ws, size_t ws_size,
                              hipStream_t stream) {
    (void)in_sizes; (void)n_in; (void)out_size; (void)ws_size;
    const float* x   = (const float*)d_in[0];
    const float* pos = (const float*)d_in[1];
    const float* gp  = (const float*)d_in[2];
    const float* ls  = (const float*)d_in[3];
    const float* al  = (const float*)d_in[4];
    const float* Wi  = (const float*)d_in[5];
    const float* bi  = (const float*)d_in[6];
    const float* g1  = (const float*)d_in[7];
    const float* b1  = (const float*)d_in[8];
    const float* Wo  = (const float*)d_in[9];
    const float* bo  = (const float*)d_in[10];
    const float* g2  = (const float*)d_in[11];
    const float* b2  = (const float*)d_in[12];
    float* out = (float*)d_out;

    float* f0 = (float*)d_ws;                              // 8 MB fp32 field
    float* f1 = f0 + (size_t)B_ * M_ * D_;                 // 8 MB ping-pong
    u16* xT  = (u16*)(f1 + (size_t)B_ * M_ * D_);          // 32 MB bf16 x^T
    u16* WiT = xT + (size_t)B_ * D_ * N_;                  // 512 KB
    u16* WoT = WiT + (size_t)D_ * D_;                      // 512 KB
    u16* enh = xT;                                         // alias: xT dead after project

    const int csBytes = 32 * 516 * sizeof(float);          // 66048 B dynamic LDS
    static bool attr_set = false;
    hipFuncSetAttribute(reinterpret_cast<const void*>(k_gemm_ln),
                        hipFuncAttributeMaxDynamicSharedMemorySize, csBytes);
    (void)attr_set;

    hipMemsetAsync(f0, 0, (size_t)B_ * M_ * D_ * sizeof(float), stream);
    k_prep_T<<<dim3(D_ / 64, N_ / 64, B_), 256, 0, stream>>>(x, xT, N_, D_);
    k_prep_T<<<dim3(D_ / 64, D_ / 64, 1), 256, 0, stream>>>(Wi, WiT, D_, D_);
    k_prep_T<<<dim3(D_ / 64, D_ / 64, 1), 256, 0, stream>>>(Wo, WoT, D_, D_);
    k_project<<<dim3(M_ / 128, D_ / 128, B_ * 8), 512, 0, stream>>>(pos, gp, ls, xT, f0);
    k_diffuse<<<dim3(M_ / 16, D_ / 256, B_), 256, 0, stream>>>(f0, WiT, bi, al, f1);
    k_diffuse<<<dim3(M_ / 16, D_ / 256, B_), 256, 0, stream>>>(f1, WiT, bi, al, f0);
    k_diffuse<<<dim3(M_ / 16, D_ / 256, B_), 256, 0, stream>>>(f0, WiT, bi, al, f1);
    k_diffuse<<<dim3(M_ / 16, D_ / 256, B_), 256, 0, stream>>>(f1, WiT, bi, al, f0);
    k_enh<<<dim3(N_ / 4, B_), 256, 0, stream>>>(x, pos, f0, g1, b1, enh);
    k_gemm_ln<<<dim3(B_ * N_ / 64), 512, csBytes, stream>>>(enh, WoT, bo, g2, b2, out);
}

// Round 5
// 246.400 us; speedup vs baseline: 1.2237x; 1.2226x over previous
//
#include <hip/hip_runtime.h>
#include <cmath>

#define B_ 8
#define N_ 4096
#define D_ 512
#define M_ 512
#define EPS_ 1e-5f
#define DT_ 0.25f

typedef unsigned short u16;
typedef unsigned int u32;
typedef __attribute__((ext_vector_type(8))) u16 u16x8;
typedef __attribute__((ext_vector_type(4))) u16 u16x4;
typedef __attribute__((ext_vector_type(8))) short bf16x8;
typedef __attribute__((ext_vector_type(4))) float f32x4;

__device__ __forceinline__ u16 f2bf(float f) {
    u32 u = __builtin_bit_cast(u32, f);
    u32 r = u + 0x7fffu + ((u >> 16) & 1u);   // round-to-nearest-even
    return (u16)(r >> 16);
}
__device__ __forceinline__ float bf2f(u16 h) {
    return __builtin_bit_cast(float, (u32)h << 16);
}

// async global->LDS, 16B per lane; lds must be wave-uniform base (+lane*16 HW)
__device__ __forceinline__ void gload16(const void* g, void* l) {
    __builtin_amdgcn_global_load_lds(
        (const __attribute__((address_space(1))) void*)g,
        (__attribute__((address_space(3))) void*)l, 16, 0, 0);
}

// ---------------------------------------------------------------------------
// Transpose + fp32->bf16: src [Z][R][C] -> dst [Z][C][R]
// ---------------------------------------------------------------------------
__global__ __launch_bounds__(256)
void k_prep_T(const float* __restrict__ src, u16* __restrict__ dst, int R, int C)
{
    __shared__ float tile[64][65];
    const int t = threadIdx.x;
    const int c0 = blockIdx.x * 64;
    const int r0 = blockIdx.y * 64;
    const int z  = blockIdx.z;
    const float* s = src + (size_t)z * R * C;
    u16* d = dst + (size_t)z * R * C;
    const int rl = t >> 4, cc = (t & 15) * 4;
#pragma unroll
    for (int i = 0; i < 4; ++i) {
        float4 v = *reinterpret_cast<const float4*>(s + (size_t)(r0 + rl + i * 16) * C + c0 + cc);
        tile[rl + i * 16][cc + 0] = v.x;
        tile[rl + i * 16][cc + 1] = v.y;
        tile[rl + i * 16][cc + 2] = v.z;
        tile[rl + i * 16][cc + 3] = v.w;
    }
    __syncthreads();
#pragma unroll
    for (int i = 0; i < 2; ++i) {
        int q = t + i * 256;
        int cl = q >> 3, rc = (q & 7) * 8;
        u16x8 o;
#pragma unroll
        for (int j = 0; j < 8; ++j) o[j] = f2bf(tile[rc + j][cl]);
        *reinterpret_cast<u16x8*>(d + (size_t)(c0 + cl) * R + r0 + rc) = o;
    }
}

// ---------------------------------------------------------------------------
// Projection: field[b] += kern[M,Nchunk] @ x[Nchunk,D] via bf16 MFMA.
// 128x128 tile, 8-way K-split over n, atomicAdd accumulate into fp32 field.
// grid (M/128, D/128, B*8), 512 thr (8 waves 2x4).
// ---------------------------------------------------------------------------
__global__ __launch_bounds__(512)
void k_project(const float* __restrict__ pos, const float* __restrict__ gp,
               const float* __restrict__ log_sigma, const u16* __restrict__ xT,
               float* __restrict__ field)
{
    __shared__ u16 As[128][72];   // kern [m][n]
    __shared__ u16 Bs[128][72];   // xT   [d][n]
    __shared__ float gs[128];
    const int t = threadIdx.x;
    const int m0 = blockIdx.x * 128, d0 = blockIdx.y * 128;
    const int z = blockIdx.z;
    const int b = z >> 3, kc = z & 7;              // 8 K-chunks of 512 n
    const int l = t & 63, wid = t >> 6;
    const int wm = wid >> 2, wn = wid & 3;

    if (t < 128) gs[t] = gp[(size_t)b * M_ + m0 + t];
    const float sigma = __expf(log_sigma[0]);
    const float ninv2s2 = -0.5f / (sigma * sigma);
    const float* pb = pos + (size_t)b * N_ + kc * 512;
    const u16* xb = xT + ((size_t)b * D_ + d0) * N_ + kc * 512;

    f32x4 acc[4][2];
#pragma unroll
    for (int i = 0; i < 4; ++i)
#pragma unroll
        for (int j = 0; j < 2; ++j) acc[i][j] = (f32x4){0.f, 0.f, 0.f, 0.f};

    const int srow = t >> 2, ssub = (t & 3) * 16;
    __syncthreads();   // gs visible

    for (int it = 0; it < 8; ++it) {
        const int n0 = it * 64;
        __syncthreads();   // protect previous tile reads
        {   // stage kern: thread does 16 exps for row srow, cols ssub..+15
            const float gm = gs[srow];
            float4 p0 = *reinterpret_cast<const float4*>(pb + n0 + ssub);
            float4 p1 = *reinterpret_cast<const float4*>(pb + n0 + ssub + 4);
            float4 p2 = *reinterpret_cast<const float4*>(pb + n0 + ssub + 8);
            float4 p3 = *reinterpret_cast<const float4*>(pb + n0 + ssub + 12);
            float dv[16] = {gm-p0.x, gm-p0.y, gm-p0.z, gm-p0.w,
                            gm-p1.x, gm-p1.y, gm-p1.z, gm-p1.w,
                            gm-p2.x, gm-p2.y, gm-p2.z, gm-p2.w,
                            gm-p3.x, gm-p3.y, gm-p3.z, gm-p3.w};
            u16x8 k0, k1;
#pragma unroll
            for (int j = 0; j < 8; ++j) k0[j] = f2bf(__expf(dv[j] * dv[j] * ninv2s2));
#pragma unroll
            for (int j = 0; j < 8; ++j) k1[j] = f2bf(__expf(dv[j+8] * dv[j+8] * ninv2s2));
            *reinterpret_cast<u16x8*>(&As[srow][ssub])     = k0;
            *reinterpret_cast<u16x8*>(&As[srow][ssub + 8]) = k1;
        }
        {   // stage xT tile
            u16x8 v0 = *reinterpret_cast<const u16x8*>(xb + (size_t)srow * N_ + n0 + ssub);
            u16x8 v1 = *reinterpret_cast<const u16x8*>(xb + (size_t)srow * N_ + n0 + ssub + 8);
            *reinterpret_cast<u16x8*>(&Bs[srow][ssub])     = v0;
            *reinterpret_cast<u16x8*>(&Bs[srow][ssub + 8]) = v1;
        }
        __syncthreads();
#pragma unroll
        for (int kk = 0; kk < 64; kk += 32) {
            const int ko = kk + (l >> 4) * 8;
            bf16x8 bfr[2];
#pragma unroll
            for (int nf = 0; nf < 2; ++nf)
                bfr[nf] = *reinterpret_cast<const bf16x8*>(&Bs[wn * 32 + nf * 16 + (l & 15)][ko]);
#pragma unroll
            for (int mf = 0; mf < 4; ++mf) {
                bf16x8 a = *reinterpret_cast<const bf16x8*>(&As[wm * 64 + mf * 16 + (l & 15)][ko]);
                acc[mf][0] = __builtin_amdgcn_mfma_f32_16x16x32_bf16(a, bfr[0], acc[mf][0], 0, 0, 0);
                acc[mf][1] = __builtin_amdgcn_mfma_f32_16x16x32_bf16(a, bfr[1], acc[mf][1], 0, 0, 0);
            }
        }
    }

    float* fb = field + (size_t)b * M_ * D_;
#pragma unroll
    for (int mf = 0; mf < 4; ++mf)
#pragma unroll
        for (int nf = 0; nf < 2; ++nf)
#pragma unroll
            for (int r = 0; r < 4; ++r) {
                const int m = m0 + wm * 64 + mf * 16 + (l >> 4) * 4 + r;
                const int d = d0 + wn * 32 + nf * 16 + (l & 15);
                unsafeAtomicAdd(fb + (size_t)m * D_ + d, acc[mf][nf][r]);
            }
}

// ---------------------------------------------------------------------------
// Diffusion step: fout = fin + dt*(alpha*lap + tanh(fin @ Wi + bi))
// grid (M/16, D/256, B), 256 thr. GEMM -> Cs stage -> coalesced row pass.
// ---------------------------------------------------------------------------
__global__ __launch_bounds__(256)
void k_diffuse(const float* __restrict__ fin, const u16* __restrict__ WiT,
               const float* __restrict__ bi, const float* __restrict__ alpha_p,
               float* __restrict__ fout)
{
    __shared__ u16 fs[16][520];      // 16.6 KB bf16 field rows
    __shared__ float Cs[16][260];    // 16.6 KB fp32 gemm stage (260: conflict-free)
    const int t = threadIdx.x;
    const int m0 = blockIdx.x * 16;
    const int cb0 = blockIdx.y * 256;
    const int b = blockIdx.z;
    const int l = t & 63, wn = t >> 6;
    const float* fb = fin + (size_t)b * M_ * D_;

    {
        const int row = t >> 4, ch = (t & 15) * 32;
        const float* src = fb + (size_t)(m0 + row) * D_ + ch;
#pragma unroll
        for (int j = 0; j < 4; ++j) {
            float4 v0 = *reinterpret_cast<const float4*>(src + j * 8);
            float4 v1 = *reinterpret_cast<const float4*>(src + j * 8 + 4);
            u16x8 o;
            o[0] = f2bf(v0.x); o[1] = f2bf(v0.y); o[2] = f2bf(v0.z); o[3] = f2bf(v0.w);
            o[4] = f2bf(v1.x); o[5] = f2bf(v1.y); o[6] = f2bf(v1.z); o[7] = f2bf(v1.w);
            *reinterpret_cast<u16x8*>(&fs[row][ch + j * 8]) = o;
        }
    }
    __syncthreads();

    f32x4 acc[4];
#pragma unroll
    for (int i = 0; i < 4; ++i) acc[i] = (f32x4){0.f, 0.f, 0.f, 0.f};

    for (int kk = 0; kk < D_; kk += 32) {
        const int ko = kk + (l >> 4) * 8;
        bf16x8 a = *reinterpret_cast<const bf16x8*>(&fs[l & 15][ko]);
#pragma unroll
        for (int nf = 0; nf < 4; ++nf) {
            bf16x8 w = *reinterpret_cast<const bf16x8*>(
                WiT + (size_t)(cb0 + wn * 64 + nf * 16 + (l & 15)) * D_ + ko);
            acc[nf] = __builtin_amdgcn_mfma_f32_16x16x32_bf16(a, w, acc[nf], 0, 0, 0);
        }
    }

    // stage gemm+bias into Cs (scatter, conflict-free by 260 stride)
#pragma unroll
    for (int nf = 0; nf < 4; ++nf) {
        const int cl = wn * 64 + nf * 16 + (l & 15);
        const float bic = bi[cb0 + cl];
#pragma unroll
        for (int r = 0; r < 4; ++r)
            Cs[(l >> 4) * 4 + r][cl] = acc[nf][r] + bic;
    }
    __syncthreads();

    // row pass: wave wn owns rows wn*4..+3, fully vectorized
    const float al = alpha_p[0];
    float* fob = fout + (size_t)b * M_ * D_;
#pragma unroll
    for (int i = 0; i < 4; ++i) {
        const int row = wn * 4 + i;
        const int m = m0 + row;
        const int mu_ = m > 0 ? m - 1 : 0;
        const int md = m < M_ - 1 ? m + 1 : M_ - 1;
        const int cl = cb0 + l * 4;
        float4 g  = *reinterpret_cast<const float4*>(&Cs[row][l * 4]);
        float4 fc = *reinterpret_cast<const float4*>(fb + (size_t)m * D_ + cl);
        float4 fu = *reinterpret_cast<const float4*>(fb + (size_t)mu_ * D_ + cl);
        float4 fd = *reinterpret_cast<const float4*>(fb + (size_t)md * D_ + cl);
        float4 o;
        o.x = fc.x + DT_ * (al * (fu.x + fd.x - 2.f * fc.x) + tanhf(g.x));
        o.y = fc.y + DT_ * (al * (fu.y + fd.y - 2.f * fc.y) + tanhf(g.y));
        o.z = fc.z + DT_ * (al * (fu.z + fd.z - 2.f * fc.z) + tanhf(g.z));
        o.w = fc.w + DT_ * (al * (fu.w + fd.w - 2.f * fc.w) + tanhf(g.w));
        *reinterpret_cast<float4*>(fob + (size_t)m * D_ + cl) = o;
    }
}

// ---------------------------------------------------------------------------
// Tail part 1: enh = LN1(lerp(field) + x) -> bf16.  Zero LDS, one wave/row.
// grid (N/4, B), 256 thr.
// ---------------------------------------------------------------------------
__global__ __launch_bounds__(256)
void k_enh(const float* __restrict__ x, const float* __restrict__ pos,
           const float* __restrict__ field, const float* __restrict__ g1,
           const float* __restrict__ b1, u16* __restrict__ enh)
{
    const int t = threadIdx.x;
    const int wid = t >> 6, l = t & 63;
    const int n = blockIdx.x * 4 + wid;
    const int b = blockIdx.y;
    const int c = l * 8;

    const float* xr = x + ((size_t)b * N_ + n) * D_ + c;
    float4 xa = *reinterpret_cast<const float4*>(xr);
    float4 xb = *reinterpret_cast<const float4*>(xr + 4);
    const float p = pos[(size_t)b * N_ + n];
    float u = p * (float)(M_ - 1);
    int i0 = (int)floorf(u);
    i0 = i0 < 0 ? 0 : (i0 > M_ - 2 ? M_ - 2 : i0);
    const float w = u - (float)i0;
    const float* fp0 = field + ((size_t)b * M_ + i0) * D_ + c;
    float4 f0a = *reinterpret_cast<const float4*>(fp0);
    float4 f0b = *reinterpret_cast<const float4*>(fp0 + 4);
    float4 f1a = *reinterpret_cast<const float4*>(fp0 + D_);
    float4 f1b = *reinterpret_cast<const float4*>(fp0 + D_ + 4);

    float s[8];
    s[0] = f0a.x + w * (f1a.x - f0a.x) + xa.x;
    s[1] = f0a.y + w * (f1a.y - f0a.y) + xa.y;
    s[2] = f0a.z + w * (f1a.z - f0a.z) + xa.z;
    s[3] = f0a.w + w * (f1a.w - f0a.w) + xa.w;
    s[4] = f0b.x + w * (f1b.x - f0b.x) + xb.x;
    s[5] = f0b.y + w * (f1b.y - f0b.y) + xb.y;
    s[6] = f0b.z + w * (f1b.z - f0b.z) + xb.z;
    s[7] = f0b.w + w * (f1b.w - f0b.w) + xb.w;

    float sum = 0.f, ss = 0.f;
#pragma unroll
    for (int j = 0; j < 8; ++j) { sum += s[j]; ss += s[j] * s[j]; }
#pragma unroll
    for (int off = 1; off <= 32; off <<= 1) {
        sum += __shfl_xor(sum, off);
        ss  += __shfl_xor(ss, off);
    }
    const float mu = sum * (1.f / 512.f);
    const float rs = rsqrtf(ss * (1.f / 512.f) - mu * mu + EPS_);

    float4 ga = *reinterpret_cast<const float4*>(g1 + c);
    float4 gb = *reinterpret_cast<const float4*>(g1 + c + 4);
    float4 ba = *reinterpret_cast<const float4*>(b1 + c);
    float4 bb = *reinterpret_cast<const float4*>(b1 + c + 4);
    u16x8 e;
    e[0] = f2bf((s[0] - mu) * rs * ga.x + ba.x);
    e[1] = f2bf((s[1] - mu) * rs * ga.y + ba.y);
    e[2] = f2bf((s[2] - mu) * rs * ga.z + ba.z);
    e[3] = f2bf((s[3] - mu) * rs * ga.w + ba.w);
    e[4] = f2bf((s[4] - mu) * rs * gb.x + bb.x);
    e[5] = f2bf((s[5] - mu) * rs * gb.y + bb.y);
    e[6] = f2bf((s[6] - mu) * rs * gb.z + bb.z);
    e[7] = f2bf((s[7] - mu) * rs * gb.w + bb.w);
    *reinterpret_cast<u16x8*>(enh + ((size_t)b * N_ + n) * D_ + c) = e;
}

// ---------------------------------------------------------------------------
// Tail part 2: out = LN2(enh @ WoT + bo + enh).
// m97-style: per-K-step LDS staging of A(64x64) and B(512x64) via
// global_load_lds w16 with chunk^(row&7) source-pre-swizzle (uniform-bank
// ds_read_b128). 2 barriers/K-step. Epilogue: Cs stage + coalesced row pass.
// grid (B*N/64), 512 thr (8 waves 2x4). Dynamic LDS 72KB (Cs reuses it).
// ---------------------------------------------------------------------------
__global__ __launch_bounds__(512, 4)
void k_gemm_ln(const u16* __restrict__ enh, const u16* __restrict__ WoT,
               const float* __restrict__ bo, const float* __restrict__ g2,
               const float* __restrict__ b2, float* __restrict__ out)
{
    extern __shared__ u16 smem[];            // 72 KB
    u16* As = smem;                          // [64][64] linear+src-swz (8 KB)
    u16* Bs = smem + 64 * 64;                // [512][64] linear+src-swz (64 KB)
    float* Cs = (float*)smem;                // [32][516] fp32, reused post-GEMM

    const int t = threadIdx.x;
    const int r0 = blockIdx.x * 64;          // row in flattened [B*N][D]
    const int l = t & 63, wid = t >> 6;
    const int wm = wid >> 2, wn = wid & 3;

    f32x4 acc[2][8];
#pragma unroll
    for (int i = 0; i < 2; ++i)
#pragma unroll
        for (int j = 0; j < 8; ++j) acc[i][j] = (f32x4){0.f, 0.f, 0.f, 0.f};

    // staging assignments (chunk = 8 bf16 = 16B)
    const int a_row = t >> 3, a_sch = t & 7;                  // A: 512 chunks
    const u16* a_src = enh + (size_t)(r0 + a_row) * D_ + (a_sch ^ (a_row & 7)) * 8;
    u16* a_dst = As + (size_t)(wid * 64) * 8;                 // wave-uniform base

    const int fr = l & 15, fj = l >> 4;                       // frag coords

    for (int ks = 0; ks < 8; ++ks) {
        const int kk = ks * 64;
        __syncthreads();                     // prev compute done (tiles reusable)
        gload16(a_src + kk, a_dst);
#pragma unroll
        for (int i = 0; i < 8; ++i) {
            const int cid = t + i * 512;                      // B chunk id
            const int brow = cid >> 3, bsch = cid & 7;
            gload16(WoT + (size_t)brow * D_ + kk + ((bsch ^ (brow & 7)) * 8),
                    Bs + (size_t)(wid * 64 + i * 512) * 8);
        }
        __syncthreads();                     // loads landed (vmcnt0 at barrier)

#pragma unroll
        for (int kl = 0; kl < 2; ++kl) {     // two k-halves of 32
            const int cbase = kl * 4 + fj;   // chunk index 0..7
            const int ar0 = wm * 32 + fr, ar1 = ar0 + 16;
            bf16x8 a0 = *reinterpret_cast<const bf16x8*>(
                As + ar0 * 64 + ((cbase ^ (ar0 & 7)) * 8));
            bf16x8 a1 = *reinterpret_cast<const bf16x8*>(
                As + ar1 * 64 + ((cbase ^ (ar1 & 7)) * 8));
#pragma unroll
            for (int nf = 0; nf < 8; ++nf) {
                const int bcol = wn * 128 + nf * 16 + fr;
                bf16x8 bw = *reinterpret_cast<const bf16x8*>(
                    Bs + bcol * 64 + ((cbase ^ (bcol & 7)) * 8));
                acc[0][nf] = __builtin_amdgcn_mfma_f32_16x16x32_bf16(a0, bw, acc[0][nf], 0, 0, 0);
                acc[1][nf] = __builtin_amdgcn_mfma_f32_16x16x32_bf16(a1, bw, acc[1][nf], 0, 0, 0);
            }
        }
    }

#pragma unroll
    for (int mf = 0; mf < 2; ++mf) {
        __syncthreads();   // pass separation (protects Cs reuse vs B reads / prev pass)
        // scatter acc + bias into Cs; localrow = wm*16 + (l>>4)*4 + r
#pragma unroll
        for (int nf = 0; nf < 8; ++nf) {
            const int col = wn * 128 + nf * 16 + fr;
            const float boc = bo[col];
#pragma unroll
            for (int r = 0; r < 4; ++r)
                Cs[(wm * 16 + fj * 4 + r) * 516 + col] = acc[mf][nf][r] + boc;
        }
        __syncthreads();
        // row pass: wave wid owns localrows wid*4..+3; cols {l*4, 256+l*4}
#pragma unroll
        for (int i = 0; i < 4; ++i) {
            const int lr = wid * 4 + i;
            const int grow = r0 + (lr >> 4) * 32 + mf * 16 + (lr & 15);
            const int c1 = l * 4, c2 = 256 + l * 4;
            float4 fa = *reinterpret_cast<const float4*>(&Cs[lr * 516 + c1]);
            float4 fb4 = *reinterpret_cast<const float4*>(&Cs[lr * 516 + c2]);
            u16x4 e1 = *reinterpret_cast<const u16x4*>(enh + (size_t)grow * D_ + c1);
            u16x4 e2 = *reinterpret_cast<const u16x4*>(enh + (size_t)grow * D_ + c2);
            float v[8];
            v[0] = fa.x + bf2f(e1[0]); v[1] = fa.y + bf2f(e1[1]);
            v[2] = fa.z + bf2f(e1[2]); v[3] = fa.w + bf2f(e1[3]);
            v[4] = fb4.x + bf2f(e2[0]); v[5] = fb4.y + bf2f(e2[1]);
            v[6] = fb4.z + bf2f(e2[2]); v[7] = fb4.w + bf2f(e2[3]);

            float sum = 0.f, ss = 0.f;
#pragma unroll
            for (int j = 0; j < 8; ++j) { sum += v[j]; ss += v[j] * v[j]; }
#pragma unroll
            for (int off = 1; off <= 32; off <<= 1) {
                sum += __shfl_xor(sum, off);
                ss  += __shfl_xor(ss, off);
            }
            const float mu = sum * (1.f / 512.f);
            const float rs = rsqrtf(ss * (1.f / 512.f) - mu * mu + EPS_);

            float4 ga = *reinterpret_cast<const float4*>(g2 + c1);
            float4 gb = *reinterpret_cast<const float4*>(g2 + c2);
            float4 ba = *reinterpret_cast<const float4*>(b2 + c1);
            float4 bb = *reinterpret_cast<const float4*>(b2 + c2);
            float4 oa, ob;
            oa.x = (v[0] - mu) * rs * ga.x + ba.x;
            oa.y = (v[1] - mu) * rs * ga.y + ba.y;
            oa.z = (v[2] - mu) * rs * ga.z + ba.z;
            oa.w = (v[3] - mu) * rs * ga.w + ba.w;
            ob.x = (v[4] - mu) * rs * gb.x + bb.x;
            ob.y = (v[5] - mu) * rs * gb.y + bb.y;
            ob.z = (v[6] - mu) * rs * gb.z + bb.z;
            ob.w = (v[7] - mu) * rs * gb.w + bb.w;
            float* orow = out + (size_t)grow * D_;
            *reinterpret_cast<float4*>(orow + c1) = oa;
            *reinterpret_cast<float4*>(orow + c2) = ob;
        }
    }
}

extern "C" void kernel_launch(void* const* d_in, const int* in_sizes, int n_in,
                              void* d_out, int out_size, void* d_ws, size_t ws_size,
                              hipStream_t stream) {
    (void)in_sizes; (void)n_in; (void)out_size; (void)ws_size;
    const float* x   = (const float*)d_in[0];
    const float* pos = (const float*)d_in[1];
    const float* gp  = (const float*)d_in[2];
    const float* ls  = (const float*)d_in[3];
    const float* al  = (const float*)d_in[4];
    const float* Wi  = (const float*)d_in[5];
    const float* bi  = (const float*)d_in[6];
    const float* g1  = (const float*)d_in[7];
    const float* b1  = (const float*)d_in[8];
    const float* Wo  = (const float*)d_in[9];
    const float* bo  = (const float*)d_in[10];
    const float* g2  = (const float*)d_in[11];
    const float* b2  = (const float*)d_in[12];
    float* out = (float*)d_out;

    float* f0 = (float*)d_ws;                              // 8 MB fp32 field
    float* f1 = f0 + (size_t)B_ * M_ * D_;                 // 8 MB ping-pong
    u16* xT  = (u16*)(f1 + (size_t)B_ * M_ * D_);          // 32 MB bf16 x^T
    u16* WiT = xT + (size_t)B_ * D_ * N_;                  // 512 KB
    u16* WoT = WiT + (size_t)D_ * D_;                      // 512 KB
    u16* enh = xT;                                         // alias: xT dead after project

    const int smBytes = 64 * 64 * 2 + 512 * 64 * 2;        // 73728 B dynamic LDS
    hipFuncSetAttribute(reinterpret_cast<const void*>(k_gemm_ln),
                        hipFuncAttributeMaxDynamicSharedMemorySize, smBytes);

    hipMemsetAsync(f0, 0, (size_t)B_ * M_ * D_ * sizeof(float), stream);
    k_prep_T<<<dim3(D_ / 64, N_ / 64, B_), 256, 0, stream>>>(x, xT, N_, D_);
    k_prep_T<<<dim3(D_ / 64, D_ / 64, 1), 256, 0, stream>>>(Wi, WiT, D_, D_);
    k_prep_T<<<dim3(D_ / 64, D_ / 64, 1), 256, 0, stream>>>(Wo, WoT, D_, D_);
    k_project<<<dim3(M_ / 128, D_ / 128, B_ * 8), 512, 0, stream>>>(pos, gp, ls, xT, f0);
    k_diffuse<<<dim3(M_ / 16, D_ / 256, B_), 256, 0, stream>>>(f0, WiT, bi, al, f1);
    k_diffuse<<<dim3(M_ / 16, D_ / 256, B_), 256, 0, stream>>>(f1, WiT, bi, al, f0);
    k_diffuse<<<dim3(M_ / 16, D_ / 256, B_), 256, 0, stream>>>(f0, WiT, bi, al, f1);
    k_diffuse<<<dim3(M_ / 16, D_ / 256, B_), 256, 0, stream>>>(f1, WiT, bi, al, f0);
    k_enh<<<dim3(N_ / 4, B_), 256, 0, stream>>>(x, pos, f0, g1, b1, enh);
    k_gemm_ln<<<dim3(B_ * N_ / 64), 512, smBytes, stream>>>(enh, WoT, bo, g2, b2, out);
}

// Round 6
// 245.109 us; speedup vs baseline: 1.2301x; 1.0053x over previous
//
#include <hip/hip_runtime.h>
#include <cmath>

#define B_ 8
#define N_ 4096
#define D_ 512
#define M_ 512
#define EPS_ 1e-5f
#define DT_ 0.25f

typedef unsigned short u16;
typedef unsigned int u32;
typedef __attribute__((ext_vector_type(8))) u16 u16x8;
typedef __attribute__((ext_vector_type(4))) u16 u16x4;
typedef __attribute__((ext_vector_type(8))) short bf16x8;
typedef __attribute__((ext_vector_type(4))) float f32x4;

__device__ __forceinline__ u16 f2bf(float f) {
    u32 u = __builtin_bit_cast(u32, f);
    u32 r = u + 0x7fffu + ((u >> 16) & 1u);   // round-to-nearest-even
    return (u16)(r >> 16);
}
__device__ __forceinline__ float bf2f(u16 h) {
    return __builtin_bit_cast(float, (u32)h << 16);
}

// async global->LDS, 16B per lane; lds must be wave-uniform base (+lane*16 HW)
__device__ __forceinline__ void gload16(const void* g, void* l) {
    __builtin_amdgcn_global_load_lds(
        (const __attribute__((address_space(1))) void*)g,
        (__attribute__((address_space(3))) void*)l, 16, 0, 0);
}

// ---------------------------------------------------------------------------
// Transpose + fp32->bf16: src [Z][R][C] -> dst [Z][C][R]
// ---------------------------------------------------------------------------
__global__ __launch_bounds__(256)
void k_prep_T(const float* __restrict__ src, u16* __restrict__ dst, int R, int C)
{
    __shared__ float tile[64][65];
    const int t = threadIdx.x;
    const int c0 = blockIdx.x * 64;
    const int r0 = blockIdx.y * 64;
    const int z  = blockIdx.z;
    const float* s = src + (size_t)z * R * C;
    u16* d = dst + (size_t)z * R * C;
    const int rl = t >> 4, cc = (t & 15) * 4;
#pragma unroll
    for (int i = 0; i < 4; ++i) {
        float4 v = *reinterpret_cast<const float4*>(s + (size_t)(r0 + rl + i * 16) * C + c0 + cc);
        tile[rl + i * 16][cc + 0] = v.x;
        tile[rl + i * 16][cc + 1] = v.y;
        tile[rl + i * 16][cc + 2] = v.z;
        tile[rl + i * 16][cc + 3] = v.w;
    }
    __syncthreads();
#pragma unroll
    for (int i = 0; i < 2; ++i) {
        int q = t + i * 256;
        int cl = q >> 3, rc = (q & 7) * 8;
        u16x8 o;
#pragma unroll
        for (int j = 0; j < 8; ++j) o[j] = f2bf(tile[rc + j][cl]);
        *reinterpret_cast<u16x8*>(d + (size_t)(c0 + cl) * R + r0 + rc) = o;
    }
}

// ---------------------------------------------------------------------------
// RBF kernel matrix: kern[b][m][n] = exp(-(g_m - p_n)^2 / (2 sigma^2)) bf16.
// grid (M/8, B), 256 thr. Thread owns 16 n-cols for 8 m-rows. Coalesced.
// ---------------------------------------------------------------------------
__global__ __launch_bounds__(256)
void k_kern(const float* __restrict__ pos, const float* __restrict__ gp,
            const float* __restrict__ log_sigma, u16* __restrict__ kern)
{
    const int t = threadIdx.x;
    const int m0 = blockIdx.x * 8;
    const int b  = blockIdx.y;
    const int n0 = t * 16;

    const float sigma = __expf(log_sigma[0]);
    const float ninv2s2 = -0.5f / (sigma * sigma);

    const float* pb = pos + (size_t)b * N_ + n0;
    float4 p0 = *reinterpret_cast<const float4*>(pb);
    float4 p1 = *reinterpret_cast<const float4*>(pb + 4);
    float4 p2 = *reinterpret_cast<const float4*>(pb + 8);
    float4 p3 = *reinterpret_cast<const float4*>(pb + 12);
    float pv[16] = {p0.x, p0.y, p0.z, p0.w, p1.x, p1.y, p1.z, p1.w,
                    p2.x, p2.y, p2.z, p2.w, p3.x, p3.y, p3.z, p3.w};

#pragma unroll
    for (int mi = 0; mi < 8; ++mi) {
        const float gm = gp[(size_t)b * M_ + m0 + mi];
        u16x8 k0, k1;
#pragma unroll
        for (int j = 0; j < 8; ++j) {
            float d = gm - pv[j];
            k0[j] = f2bf(__expf(d * d * ninv2s2));
        }
#pragma unroll
        for (int j = 0; j < 8; ++j) {
            float d = gm - pv[j + 8];
            k1[j] = f2bf(__expf(d * d * ninv2s2));
        }
        u16* dst = kern + ((size_t)(b * M_ + m0 + mi)) * N_ + n0;
        *reinterpret_cast<u16x8*>(dst)     = k0;
        *reinterpret_cast<u16x8*>(dst + 8) = k1;
    }
}

// ---------------------------------------------------------------------------
// Projection GEMM (m97-style): field[b][m-tile][:] += kern-chunk @ xT-chunk.
// grid (M/64, B, 4 n-chunks of 1024), 512 thr (8 waves 2x4). 72KB dyn LDS.
// Both operands via global_load_lds w16, chunk^(row&7) source-pre-swizzle.
// Cross-chunk accumulation via coalesced unsafeAtomicAdd.
// ---------------------------------------------------------------------------
__global__ __launch_bounds__(512, 4)
void k_projgemm(const u16* __restrict__ kern, const u16* __restrict__ xT,
                float* __restrict__ field)
{
    extern __shared__ u16 smem[];            // 72 KB
    u16* As = smem;                          // [64][64] kern rows (8 KB)
    u16* Bs = smem + 64 * 64;                // [512][64] xT rows (64 KB)

    const int t = threadIdx.x;
    const int m0 = blockIdx.x * 64;
    const int b  = blockIdx.y;
    const int nc0 = blockIdx.z * 1024;       // n-chunk base
    const int l = t & 63, wid = t >> 6;
    const int wm = wid >> 2, wn = wid & 3;

    f32x4 acc[2][8];
#pragma unroll
    for (int i = 0; i < 2; ++i)
#pragma unroll
        for (int j = 0; j < 8; ++j) acc[i][j] = (f32x4){0.f, 0.f, 0.f, 0.f};

    // staging assignments (chunk = 8 bf16 = 16B)
    const int a_row = t >> 3, a_sch = t & 7;
    const u16* a_src = kern + ((size_t)(b * M_ + m0 + a_row)) * N_ + nc0
                            + (a_sch ^ (a_row & 7)) * 8;
    u16* a_dst = As + (size_t)(wid * 64) * 8;     // wave-uniform base
    const u16* xb = xT + (size_t)b * D_ * N_ + nc0;

    const int fr = l & 15, fj = l >> 4;

    for (int ks = 0; ks < 16; ++ks) {
        const int kk = ks * 64;
        __syncthreads();                     // prev compute done
        gload16(a_src + kk, a_dst);
#pragma unroll
        for (int i = 0; i < 8; ++i) {
            const int cid = t + i * 512;
            const int brow = cid >> 3, bsch = cid & 7;
            gload16(xb + (size_t)brow * N_ + kk + ((bsch ^ (brow & 7)) * 8),
                    Bs + (size_t)(wid * 64 + i * 512) * 8);
        }
        __syncthreads();                     // loads landed

#pragma unroll
        for (int kl = 0; kl < 2; ++kl) {
            const int cbase = kl * 4 + fj;
            const int ar0 = wm * 32 + fr, ar1 = ar0 + 16;
            bf16x8 a0 = *reinterpret_cast<const bf16x8*>(
                As + ar0 * 64 + ((cbase ^ (ar0 & 7)) * 8));
            bf16x8 a1 = *reinterpret_cast<const bf16x8*>(
                As + ar1 * 64 + ((cbase ^ (ar1 & 7)) * 8));
#pragma unroll
            for (int nf = 0; nf < 8; ++nf) {
                const int bcol = wn * 128 + nf * 16 + fr;
                bf16x8 bw = *reinterpret_cast<const bf16x8*>(
                    Bs + bcol * 64 + ((cbase ^ (bcol & 7)) * 8));
                acc[0][nf] = __builtin_amdgcn_mfma_f32_16x16x32_bf16(a0, bw, acc[0][nf], 0, 0, 0);
                acc[1][nf] = __builtin_amdgcn_mfma_f32_16x16x32_bf16(a1, bw, acc[1][nf], 0, 0, 0);
            }
        }
    }

    float* fb = field + (size_t)b * M_ * D_;
#pragma unroll
    for (int mf = 0; mf < 2; ++mf)
#pragma unroll
        for (int nf = 0; nf < 8; ++nf) {
            const int col = wn * 128 + nf * 16 + fr;
#pragma unroll
            for (int r = 0; r < 4; ++r) {
                const int m = m0 + wm * 32 + mf * 16 + fj * 4 + r;
                unsafeAtomicAdd(fb + (size_t)m * D_ + col, acc[mf][nf][r]);
            }
        }
}

// ---------------------------------------------------------------------------
// Diffusion step: fout = fin + dt*(alpha*lap + tanh(fin @ Wi + bi))
// grid (M/16, D/256, B), 256 thr. GEMM -> Cs stage -> coalesced row pass.
// ---------------------------------------------------------------------------
__global__ __launch_bounds__(256)
void k_diffuse(const float* __restrict__ fin, const u16* __restrict__ WiT,
               const float* __restrict__ bi, const float* __restrict__ alpha_p,
               float* __restrict__ fout)
{
    __shared__ u16 fs[16][520];      // 16.6 KB bf16 field rows
    __shared__ float Cs[16][260];    // 16.6 KB fp32 gemm stage (260: conflict-free)
    const int t = threadIdx.x;
    const int m0 = blockIdx.x * 16;
    const int cb0 = blockIdx.y * 256;
    const int b = blockIdx.z;
    const int l = t & 63, wn = t >> 6;
    const float* fb = fin + (size_t)b * M_ * D_;

    {
        const int row = t >> 4, ch = (t & 15) * 32;
        const float* src = fb + (size_t)(m0 + row) * D_ + ch;
#pragma unroll
        for (int j = 0; j < 4; ++j) {
            float4 v0 = *reinterpret_cast<const float4*>(src + j * 8);
            float4 v1 = *reinterpret_cast<const float4*>(src + j * 8 + 4);
            u16x8 o;
            o[0] = f2bf(v0.x); o[1] = f2bf(v0.y); o[2] = f2bf(v0.z); o[3] = f2bf(v0.w);
            o[4] = f2bf(v1.x); o[5] = f2bf(v1.y); o[6] = f2bf(v1.z); o[7] = f2bf(v1.w);
            *reinterpret_cast<u16x8*>(&fs[row][ch + j * 8]) = o;
        }
    }
    __syncthreads();

    f32x4 acc[4];
#pragma unroll
    for (int i = 0; i < 4; ++i) acc[i] = (f32x4){0.f, 0.f, 0.f, 0.f};

    for (int kk = 0; kk < D_; kk += 32) {
        const int ko = kk + (l >> 4) * 8;
        bf16x8 a = *reinterpret_cast<const bf16x8*>(&fs[l & 15][ko]);
#pragma unroll
        for (int nf = 0; nf < 4; ++nf) {
            bf16x8 w = *reinterpret_cast<const bf16x8*>(
                WiT + (size_t)(cb0 + wn * 64 + nf * 16 + (l & 15)) * D_ + ko);
            acc[nf] = __builtin_amdgcn_mfma_f32_16x16x32_bf16(a, w, acc[nf], 0, 0, 0);
        }
    }

    // stage gemm+bias into Cs (scatter, conflict-free by 260 stride)
#pragma unroll
    for (int nf = 0; nf < 4; ++nf) {
        const int cl = wn * 64 + nf * 16 + (l & 15);
        const float bic = bi[cb0 + cl];
#pragma unroll
        for (int r = 0; r < 4; ++r)
            Cs[(l >> 4) * 4 + r][cl] = acc[nf][r] + bic;
    }
    __syncthreads();

    // row pass: wave wn owns rows wn*4..+3, fully vectorized
    const float al = alpha_p[0];
    float* fob = fout + (size_t)b * M_ * D_;
#pragma unroll
    for (int i = 0; i < 4; ++i) {
        const int row = wn * 4 + i;
        const int m = m0 + row;
        const int mu_ = m > 0 ? m - 1 : 0;
        const int md = m < M_ - 1 ? m + 1 : M_ - 1;
        const int cl = cb0 + l * 4;
        float4 g  = *reinterpret_cast<const float4*>(&Cs[row][l * 4]);
        float4 fc = *reinterpret_cast<const float4*>(fb + (size_t)m * D_ + cl);
        float4 fu = *reinterpret_cast<const float4*>(fb + (size_t)mu_ * D_ + cl);
        float4 fd = *reinterpret_cast<const float4*>(fb + (size_t)md * D_ + cl);
        float4 o;
        o.x = fc.x + DT_ * (al * (fu.x + fd.x - 2.f * fc.x) + tanhf(g.x));
        o.y = fc.y + DT_ * (al * (fu.y + fd.y - 2.f * fc.y) + tanhf(g.y));
        o.z = fc.z + DT_ * (al * (fu.z + fd.z - 2.f * fc.z) + tanhf(g.z));
        o.w = fc.w + DT_ * (al * (fu.w + fd.w - 2.f * fc.w) + tanhf(g.w));
        *reinterpret_cast<float4*>(fob + (size_t)m * D_ + cl) = o;
    }
}

// ---------------------------------------------------------------------------
// Tail part 1: enh = LN1(lerp(field) + x) -> bf16.  Zero LDS, one wave/row.
// grid (N/4, B), 256 thr.
// ---------------------------------------------------------------------------
__global__ __launch_bounds__(256)
void k_enh(const float* __restrict__ x, const float* __restrict__ pos,
           const float* __restrict__ field, const float* __restrict__ g1,
           const float* __restrict__ b1, u16* __restrict__ enh)
{
    const int t = threadIdx.x;
    const int wid = t >> 6, l = t & 63;
    const int n = blockIdx.x * 4 + wid;
    const int b = blockIdx.y;
    const int c = l * 8;

    const float* xr = x + ((size_t)b * N_ + n) * D_ + c;
    float4 xa = *reinterpret_cast<const float4*>(xr);
    float4 xb = *reinterpret_cast<const float4*>(xr + 4);
    const float p = pos[(size_t)b * N_ + n];
    float u = p * (float)(M_ - 1);
    int i0 = (int)floorf(u);
    i0 = i0 < 0 ? 0 : (i0 > M_ - 2 ? M_ - 2 : i0);
    const float w = u - (float)i0;
    const float* fp0 = field + ((size_t)b * M_ + i0) * D_ + c;
    float4 f0a = *reinterpret_cast<const float4*>(fp0);
    float4 f0b = *reinterpret_cast<const float4*>(fp0 + 4);
    float4 f1a = *reinterpret_cast<const float4*>(fp0 + D_);
    float4 f1b = *reinterpret_cast<const float4*>(fp0 + D_ + 4);

    float s[8];
    s[0] = f0a.x + w * (f1a.x - f0a.x) + xa.x;
    s[1] = f0a.y + w * (f1a.y - f0a.y) + xa.y;
    s[2] = f0a.z + w * (f1a.z - f0a.z) + xa.z;
    s[3] = f0a.w + w * (f1a.w - f0a.w) + xa.w;
    s[4] = f0b.x + w * (f1b.x - f0b.x) + xb.x;
    s[5] = f0b.y + w * (f1b.y - f0b.y) + xb.y;
    s[6] = f0b.z + w * (f1b.z - f0b.z) + xb.z;
    s[7] = f0b.w + w * (f1b.w - f0b.w) + xb.w;

    float sum = 0.f, ss = 0.f;
#pragma unroll
    for (int j = 0; j < 8; ++j) { sum += s[j]; ss += s[j] * s[j]; }
#pragma unroll
    for (int off = 1; off <= 32; off <<= 1) {
        sum += __shfl_xor(sum, off);
        ss  += __shfl_xor(ss, off);
    }
    const float mu = sum * (1.f / 512.f);
    const float rs = rsqrtf(ss * (1.f / 512.f) - mu * mu + EPS_);

    float4 ga = *reinterpret_cast<const float4*>(g1 + c);
    float4 gb = *reinterpret_cast<const float4*>(g1 + c + 4);
    float4 ba = *reinterpret_cast<const float4*>(b1 + c);
    float4 bb = *reinterpret_cast<const float4*>(b1 + c + 4);
    u16x8 e;
    e[0] = f2bf((s[0] - mu) * rs * ga.x + ba.x);
    e[1] = f2bf((s[1] - mu) * rs * ga.y + ba.y);
    e[2] = f2bf((s[2] - mu) * rs * ga.z + ba.z);
    e[3] = f2bf((s[3] - mu) * rs * ga.w + ba.w);
    e[4] = f2bf((s[4] - mu) * rs * gb.x + bb.x);
    e[5] = f2bf((s[5] - mu) * rs * gb.y + bb.y);
    e[6] = f2bf((s[6] - mu) * rs * gb.z + bb.z);
    e[7] = f2bf((s[7] - mu) * rs * gb.w + bb.w);
    *reinterpret_cast<u16x8*>(enh + ((size_t)b * N_ + n) * D_ + c) = e;
}

// ---------------------------------------------------------------------------
// Tail part 2: out = LN2(enh @ WoT + bo + enh).
// m97-style: per-K-step LDS staging of A(64x64) and B(512x64) via
// global_load_lds w16 with chunk^(row&7) source-pre-swizzle.
// grid (B*N/64), 512 thr (8 waves 2x4). Dynamic LDS 72KB (Cs reuses it).
// ---------------------------------------------------------------------------
__global__ __launch_bounds__(512, 4)
void k_gemm_ln(const u16* __restrict__ enh, const u16* __restrict__ WoT,
               const float* __restrict__ bo, const float* __restrict__ g2,
               const float* __restrict__ b2, float* __restrict__ out)
{
    extern __shared__ u16 smem[];            // 72 KB
    u16* As = smem;                          // [64][64] linear+src-swz (8 KB)
    u16* Bs = smem + 64 * 64;                // [512][64] linear+src-swz (64 KB)
    float* Cs = (float*)smem;                // [32][516] fp32, reused post-GEMM

    const int t = threadIdx.x;
    const int r0 = blockIdx.x * 64;          // row in flattened [B*N][D]
    const int l = t & 63, wid = t >> 6;
    const int wm = wid >> 2, wn = wid & 3;

    f32x4 acc[2][8];
#pragma unroll
    for (int i = 0; i < 2; ++i)
#pragma unroll
        for (int j = 0; j < 8; ++j) acc[i][j] = (f32x4){0.f, 0.f, 0.f, 0.f};

    // staging assignments (chunk = 8 bf16 = 16B)
    const int a_row = t >> 3, a_sch = t & 7;                  // A: 512 chunks
    const u16* a_src = enh + (size_t)(r0 + a_row) * D_ + (a_sch ^ (a_row & 7)) * 8;
    u16* a_dst = As + (size_t)(wid * 64) * 8;                 // wave-uniform base

    const int fr = l & 15, fj = l >> 4;                       // frag coords

    for (int ks = 0; ks < 8; ++ks) {
        const int kk = ks * 64;
        __syncthreads();                     // prev compute done (tiles reusable)
        gload16(a_src + kk, a_dst);
#pragma unroll
        for (int i = 0; i < 8; ++i) {
            const int cid = t + i * 512;                      // B chunk id
            const int brow = cid >> 3, bsch = cid & 7;
            gload16(WoT + (size_t)brow * D_ + kk + ((bsch ^ (brow & 7)) * 8),
                    Bs + (size_t)(wid * 64 + i * 512) * 8);
        }
        __syncthreads();                     // loads landed (vmcnt0 at barrier)

#pragma unroll
        for (int kl = 0; kl < 2; ++kl) {     // two k-halves of 32
            const int cbase = kl * 4 + fj;   // chunk index 0..7
            const int ar0 = wm * 32 + fr, ar1 = ar0 + 16;
            bf16x8 a0 = *reinterpret_cast<const bf16x8*>(
                As + ar0 * 64 + ((cbase ^ (ar0 & 7)) * 8));
            bf16x8 a1 = *reinterpret_cast<const bf16x8*>(
                As + ar1 * 64 + ((cbase ^ (ar1 & 7)) * 8));
#pragma unroll
            for (int nf = 0; nf < 8; ++nf) {
                const int bcol = wn * 128 + nf * 16 + fr;
                bf16x8 bw = *reinterpret_cast<const bf16x8*>(
                    Bs + bcol * 64 + ((cbase ^ (bcol & 7)) * 8));
                acc[0][nf] = __builtin_amdgcn_mfma_f32_16x16x32_bf16(a0, bw, acc[0][nf], 0, 0, 0);
                acc[1][nf] = __builtin_amdgcn_mfma_f32_16x16x32_bf16(a1, bw, acc[1][nf], 0, 0, 0);
            }
        }
    }

#pragma unroll
    for (int mf = 0; mf < 2; ++mf) {
        __syncthreads();   // pass separation (protects Cs reuse vs B reads / prev pass)
        // scatter acc + bias into Cs; localrow = wm*16 + (l>>4)*4 + r
#pragma unroll
        for (int nf = 0; nf < 8; ++nf) {
            const int col = wn * 128 + nf * 16 + fr;
            const float boc = bo[col];
#pragma unroll
            for (int r = 0; r < 4; ++r)
                Cs[(wm * 16 + fj * 4 + r) * 516 + col] = acc[mf][nf][r] + boc;
        }
        __syncthreads();
        // row pass: wave wid owns localrows wid*4..+3; cols {l*4, 256+l*4}
#pragma unroll
        for (int i = 0; i < 4; ++i) {
            const int lr = wid * 4 + i;
            const int grow = r0 + (lr >> 4) * 32 + mf * 16 + (lr & 15);
            const int c1 = l * 4, c2 = 256 + l * 4;
            float4 fa = *reinterpret_cast<const float4*>(&Cs[lr * 516 + c1]);
            float4 fb4 = *reinterpret_cast<const float4*>(&Cs[lr * 516 + c2]);
            u16x4 e1 = *reinterpret_cast<const u16x4*>(enh + (size_t)grow * D_ + c1);
            u16x4 e2 = *reinterpret_cast<const u16x4*>(enh + (size_t)grow * D_ + c2);
            float v[8];
            v[0] = fa.x + bf2f(e1[0]); v[1] = fa.y + bf2f(e1[1]);
            v[2] = fa.z + bf2f(e1[2]); v[3] = fa.w + bf2f(e1[3]);
            v[4] = fb4.x + bf2f(e2[0]); v[5] = fb4.y + bf2f(e2[1]);
            v[6] = fb4.z + bf2f(e2[2]); v[7] = fb4.w + bf2f(e2[3]);

            float sum = 0.f, ss = 0.f;
#pragma unroll
            for (int j = 0; j < 8; ++j) { sum += v[j]; ss += v[j] * v[j]; }
#pragma unroll
            for (int off = 1; off <= 32; off <<= 1) {
                sum += __shfl_xor(sum, off);
                ss  += __shfl_xor(ss, off);
            }
            const float mu = sum * (1.f / 512.f);
            const float rs = rsqrtf(ss * (1.f / 512.f) - mu * mu + EPS_);

            float4 ga = *reinterpret_cast<const float4*>(g2 + c1);
            float4 gb = *reinterpret_cast<const float4*>(g2 + c2);
            float4 ba = *reinterpret_cast<const float4*>(b2 + c1);
            float4 bb = *reinterpret_cast<const float4*>(b2 + c2);
            float4 oa, ob;
            oa.x = (v[0] - mu) * rs * ga.x + ba.x;
            oa.y = (v[1] - mu) * rs * ga.y + ba.y;
            oa.z = (v[2] - mu) * rs * ga.z + ba.z;
            oa.w = (v[3] - mu) * rs * ga.w + ba.w;
            ob.x = (v[4] - mu) * rs * gb.x + bb.x;
            ob.y = (v[5] - mu) * rs * gb.y + bb.y;
            ob.z = (v[6] - mu) * rs * gb.z + bb.z;
            ob.w = (v[7] - mu) * rs * gb.w + bb.w;
            float* orow = out + (size_t)grow * D_;
            *reinterpret_cast<float4*>(orow + c1) = oa;
            *reinterpret_cast<float4*>(orow + c2) = ob;
        }
    }
}

extern "C" void kernel_launch(void* const* d_in, const int* in_sizes, int n_in,
                              void* d_out, int out_size, void* d_ws, size_t ws_size,
                              hipStream_t stream) {
    (void)in_sizes; (void)n_in; (void)out_size; (void)ws_size;
    const float* x   = (const float*)d_in[0];
    const float* pos = (const float*)d_in[1];
    const float* gp  = (const float*)d_in[2];
    const float* ls  = (const float*)d_in[3];
    const float* al  = (const float*)d_in[4];
    const float* Wi  = (const float*)d_in[5];
    const float* bi  = (const float*)d_in[6];
    const float* g1  = (const float*)d_in[7];
    const float* b1  = (const float*)d_in[8];
    const float* Wo  = (const float*)d_in[9];
    const float* bo  = (const float*)d_in[10];
    const float* g2  = (const float*)d_in[11];
    const float* b2  = (const float*)d_in[12];
    float* out = (float*)d_out;

    float* f0 = (float*)d_ws;                              // 8 MB fp32 field
    float* f1 = f0 + (size_t)B_ * M_ * D_;                 // 8 MB ping-pong
    u16* xT  = (u16*)(f1 + (size_t)B_ * M_ * D_);          // 32 MB bf16 x^T
    u16* WiT = xT + (size_t)B_ * D_ * N_;                  // 512 KB
    u16* WoT = WiT + (size_t)D_ * D_;                      // 512 KB
    u16* enh = xT;                                         // alias: xT dead after project
    u16* kern = (u16*)d_out;                               // 32 MB scratch in d_out
                                                           // (dead before k_gemm_ln writes)

    const int smBytes = 64 * 64 * 2 + 512 * 64 * 2;        // 73728 B dynamic LDS
    hipFuncSetAttribute(reinterpret_cast<const void*>(k_gemm_ln),
                        hipFuncAttributeMaxDynamicSharedMemorySize, smBytes);
    hipFuncSetAttribute(reinterpret_cast<const void*>(k_projgemm),
                        hipFuncAttributeMaxDynamicSharedMemorySize, smBytes);

    hipMemsetAsync(f0, 0, (size_t)B_ * M_ * D_ * sizeof(float), stream);
    k_kern<<<dim3(M_ / 8, B_), 256, 0, stream>>>(pos, gp, ls, kern);
    k_prep_T<<<dim3(D_ / 64, N_ / 64, B_), 256, 0, stream>>>(x, xT, N_, D_);
    k_prep_T<<<dim3(D_ / 64, D_ / 64, 1), 256, 0, stream>>>(Wi, WiT, D_, D_);
    k_prep_T<<<dim3(D_ / 64, D_ / 64, 1), 256, 0, stream>>>(Wo, WoT, D_, D_);
    k_projgemm<<<dim3(M_ / 64, B_, 4), 512, smBytes, stream>>>(kern, xT, f0);
    k_diffuse<<<dim3(M_ / 16, D_ / 256, B_), 256, 0, stream>>>(f0, WiT, bi, al, f1);
    k_diffuse<<<dim3(M_ / 16, D_ / 256, B_), 256, 0, stream>>>(f1, WiT, bi, al, f0);
    k_diffuse<<<dim3(M_ / 16, D_ / 256, B_), 256, 0, stream>>>(f0, WiT, bi, al, f1);
    k_diffuse<<<dim3(M_ / 16, D_ / 256, B_), 256, 0, stream>>>(f1, WiT, bi, al, f0);
    k_enh<<<dim3(N_ / 4, B_), 256, 0, stream>>>(x, pos, f0, g1, b1, enh);
    k_gemm_ln<<<dim3(B_ * N_ / 64), 512, smBytes, stream>>>(enh, WoT, bo, g2, b2, out);
}

// Round 7
// 231.701 us; speedup vs baseline: 1.3013x; 1.0579x over previous
//
#include <hip/hip_runtime.h>
#include <cmath>

#define B_ 8
#define N_ 4096
#define D_ 512
#define M_ 512
#define EPS_ 1e-5f
#define DT_ 0.25f

typedef unsigned short u16;
typedef unsigned int u32;
typedef __attribute__((ext_vector_type(8))) u16 u16x8;
typedef __attribute__((ext_vector_type(4))) u16 u16x4;
typedef __attribute__((ext_vector_type(8))) short bf16x8;
typedef __attribute__((ext_vector_type(4))) float f32x4;

__device__ __forceinline__ u16 f2bf(float f) {
    u32 u = __builtin_bit_cast(u32, f);
    u32 r = u + 0x7fffu + ((u >> 16) & 1u);   // round-to-nearest-even
    return (u16)(r >> 16);
}
__device__ __forceinline__ float bf2f(u16 h) {
    return __builtin_bit_cast(float, (u32)h << 16);
}

// async global->LDS, 16B per lane; lds must be wave-uniform base (+lane*16 HW)
__device__ __forceinline__ void gload16(const void* g, void* l) {
    __builtin_amdgcn_global_load_lds(
        (const __attribute__((address_space(1))) void*)g,
        (__attribute__((address_space(3))) void*)l, 16, 0, 0);
}

// ---------------------------------------------------------------------------
// Transpose + fp32->bf16: src [Z][R][C] -> dst [Z][C][R]
// ---------------------------------------------------------------------------
__global__ __launch_bounds__(256)
void k_prep_T(const float* __restrict__ src, u16* __restrict__ dst, int R, int C)
{
    __shared__ float tile[64][65];
    const int t = threadIdx.x;
    const int c0 = blockIdx.x * 64;
    const int r0 = blockIdx.y * 64;
    const int z  = blockIdx.z;
    const float* s = src + (size_t)z * R * C;
    u16* d = dst + (size_t)z * R * C;
    const int rl = t >> 4, cc = (t & 15) * 4;
#pragma unroll
    for (int i = 0; i < 4; ++i) {
        float4 v = *reinterpret_cast<const float4*>(s + (size_t)(r0 + rl + i * 16) * C + c0 + cc);
        tile[rl + i * 16][cc + 0] = v.x;
        tile[rl + i * 16][cc + 1] = v.y;
        tile[rl + i * 16][cc + 2] = v.z;
        tile[rl + i * 16][cc + 3] = v.w;
    }
    __syncthreads();
#pragma unroll
    for (int i = 0; i < 2; ++i) {
        int q = t + i * 256;
        int cl = q >> 3, rc = (q & 7) * 8;
        u16x8 o;
#pragma unroll
        for (int j = 0; j < 8; ++j) o[j] = f2bf(tile[rc + j][cl]);
        *reinterpret_cast<u16x8*>(d + (size_t)(c0 + cl) * R + r0 + rc) = o;
    }
}

// ---------------------------------------------------------------------------
// RBF kernel matrix: kern[b][m][n] = exp(-(g_m - p_n)^2 / (2 sigma^2)) bf16.
// grid (M/8, B), 256 thr. Thread owns 16 n-cols for 8 m-rows. Coalesced.
// ---------------------------------------------------------------------------
__global__ __launch_bounds__(256)
void k_kern(const float* __restrict__ pos, const float* __restrict__ gp,
            const float* __restrict__ log_sigma, u16* __restrict__ kern)
{
    const int t = threadIdx.x;
    const int m0 = blockIdx.x * 8;
    const int b  = blockIdx.y;
    const int n0 = t * 16;

    const float sigma = __expf(log_sigma[0]);
    const float ninv2s2 = -0.5f / (sigma * sigma);

    const float* pb = pos + (size_t)b * N_ + n0;
    float4 p0 = *reinterpret_cast<const float4*>(pb);
    float4 p1 = *reinterpret_cast<const float4*>(pb + 4);
    float4 p2 = *reinterpret_cast<const float4*>(pb + 8);
    float4 p3 = *reinterpret_cast<const float4*>(pb + 12);
    float pv[16] = {p0.x, p0.y, p0.z, p0.w, p1.x, p1.y, p1.z, p1.w,
                    p2.x, p2.y, p2.z, p2.w, p3.x, p3.y, p3.z, p3.w};

#pragma unroll
    for (int mi = 0; mi < 8; ++mi) {
        const float gm = gp[(size_t)b * M_ + m0 + mi];
        u16x8 k0, k1;
#pragma unroll
        for (int j = 0; j < 8; ++j) {
            float d = gm - pv[j];
            k0[j] = f2bf(__expf(d * d * ninv2s2));
        }
#pragma unroll
        for (int j = 0; j < 8; ++j) {
            float d = gm - pv[j + 8];
            k1[j] = f2bf(__expf(d * d * ninv2s2));
        }
        u16* dst = kern + ((size_t)(b * M_ + m0 + mi)) * N_ + n0;
        *reinterpret_cast<u16x8*>(dst)     = k0;
        *reinterpret_cast<u16x8*>(dst + 8) = k1;
    }
}

// ---------------------------------------------------------------------------
// Projection GEMM (m97-style): field[b][m-tile][:] += kern-chunk @ xT-chunk.
// 1D grid of 256 blocks, XCD-swizzled so the 8 m-tile blocks sharing one
// (b, n-chunk) xT slab land on the SAME XCD (L2 reuse instead of 8x HBM).
// 512 thr (8 waves 2x4), 72KB dyn LDS, global_load_lds w16, src-pre-swizzle.
// Cross-chunk accumulation via coalesced unsafeAtomicAdd.
// ---------------------------------------------------------------------------
__global__ __launch_bounds__(512, 4)
void k_projgemm(const u16* __restrict__ kern, const u16* __restrict__ xT,
                float* __restrict__ field)
{
    extern __shared__ u16 smem[];            // 72 KB
    u16* As = smem;                          // [64][64] kern rows (8 KB)
    u16* Bs = smem + 64 * 64;                // [512][64] xT rows (64 KB)

    const int t = threadIdx.x;
    // XCD-aware decode: dispatch d -> (mtile, b, chunk) with all 8 mtiles of
    // a (b,chunk) group sharing d%8 (same XCD under round-robin dispatch).
    const int d = blockIdx.x;                // 0..255
    const int xcd = d & 7;
    const int q = d >> 3;                    // 0..31
    const int mtile = q & 7;
    const int gq = q >> 3;                   // 0..3
    const int g = gq * 8 + xcd;              // group id 0..31
    const int b = g & 7;
    const int m0 = mtile * 64;
    const int nc0 = (g >> 3) * 1024;         // n-chunk base

    const int l = t & 63, wid = t >> 6;
    const int wm = wid >> 2, wn = wid & 3;

    f32x4 acc[2][8];
#pragma unroll
    for (int i = 0; i < 2; ++i)
#pragma unroll
        for (int j = 0; j < 8; ++j) acc[i][j] = (f32x4){0.f, 0.f, 0.f, 0.f};

    // staging assignments (chunk = 8 bf16 = 16B)
    const int a_row = t >> 3, a_sch = t & 7;
    const u16* a_src = kern + ((size_t)(b * M_ + m0 + a_row)) * N_ + nc0
                            + (a_sch ^ (a_row & 7)) * 8;
    u16* a_dst = As + (size_t)(wid * 64) * 8;     // wave-uniform base
    const u16* xb = xT + (size_t)b * D_ * N_ + nc0;

    const int fr = l & 15, fj = l >> 4;

    for (int ks = 0; ks < 16; ++ks) {
        const int kk = ks * 64;
        __syncthreads();                     // prev compute done
        gload16(a_src + kk, a_dst);
#pragma unroll
        for (int i = 0; i < 8; ++i) {
            const int cid = t + i * 512;
            const int brow = cid >> 3, bsch = cid & 7;
            gload16(xb + (size_t)brow * N_ + kk + ((bsch ^ (brow & 7)) * 8),
                    Bs + (size_t)(wid * 64 + i * 512) * 8);
        }
        __syncthreads();                     // loads landed

#pragma unroll
        for (int kl = 0; kl < 2; ++kl) {
            const int cbase = kl * 4 + fj;
            const int ar0 = wm * 32 + fr, ar1 = ar0 + 16;
            bf16x8 a0 = *reinterpret_cast<const bf16x8*>(
                As + ar0 * 64 + ((cbase ^ (ar0 & 7)) * 8));
            bf16x8 a1 = *reinterpret_cast<const bf16x8*>(
                As + ar1 * 64 + ((cbase ^ (ar1 & 7)) * 8));
#pragma unroll
            for (int nf = 0; nf < 8; ++nf) {
                const int bcol = wn * 128 + nf * 16 + fr;
                bf16x8 bw = *reinterpret_cast<const bf16x8*>(
                    Bs + bcol * 64 + ((cbase ^ (bcol & 7)) * 8));
                acc[0][nf] = __builtin_amdgcn_mfma_f32_16x16x32_bf16(a0, bw, acc[0][nf], 0, 0, 0);
                acc[1][nf] = __builtin_amdgcn_mfma_f32_16x16x32_bf16(a1, bw, acc[1][nf], 0, 0, 0);
            }
        }
    }

    float* fb = field + (size_t)b * M_ * D_;
#pragma unroll
    for (int mf = 0; mf < 2; ++mf)
#pragma unroll
        for (int nf = 0; nf < 8; ++nf) {
            const int col = wn * 128 + nf * 16 + fr;
#pragma unroll
            for (int r = 0; r < 4; ++r) {
                const int m = m0 + wm * 32 + mf * 16 + fj * 4 + r;
                unsafeAtomicAdd(fb + (size_t)m * D_ + col, acc[mf][nf][r]);
            }
        }
}

// ---------------------------------------------------------------------------
// Diffusion step: fout = fin + dt*(alpha*lap + tanh(fin @ Wi + bi))
// grid (M/16, D/256, B), 256 thr. GEMM -> Cs stage -> coalesced row pass.
// ---------------------------------------------------------------------------
__global__ __launch_bounds__(256)
void k_diffuse(const float* __restrict__ fin, const u16* __restrict__ WiT,
               const float* __restrict__ bi, const float* __restrict__ alpha_p,
               float* __restrict__ fout)
{
    __shared__ u16 fs[16][520];      // 16.6 KB bf16 field rows
    __shared__ float Cs[16][260];    // 16.6 KB fp32 gemm stage (260: conflict-free)
    const int t = threadIdx.x;
    const int m0 = blockIdx.x * 16;
    const int cb0 = blockIdx.y * 256;
    const int b = blockIdx.z;
    const int l = t & 63, wn = t >> 6;
    const float* fb = fin + (size_t)b * M_ * D_;

    {
        const int row = t >> 4, ch = (t & 15) * 32;
        const float* src = fb + (size_t)(m0 + row) * D_ + ch;
#pragma unroll
        for (int j = 0; j < 4; ++j) {
            float4 v0 = *reinterpret_cast<const float4*>(src + j * 8);
            float4 v1 = *reinterpret_cast<const float4*>(src + j * 8 + 4);
            u16x8 o;
            o[0] = f2bf(v0.x); o[1] = f2bf(v0.y); o[2] = f2bf(v0.z); o[3] = f2bf(v0.w);
            o[4] = f2bf(v1.x); o[5] = f2bf(v1.y); o[6] = f2bf(v1.z); o[7] = f2bf(v1.w);
            *reinterpret_cast<u16x8*>(&fs[row][ch + j * 8]) = o;
        }
    }
    __syncthreads();

    f32x4 acc[4];
#pragma unroll
    for (int i = 0; i < 4; ++i) acc[i] = (f32x4){0.f, 0.f, 0.f, 0.f};

    for (int kk = 0; kk < D_; kk += 32) {
        const int ko = kk + (l >> 4) * 8;
        bf16x8 a = *reinterpret_cast<const bf16x8*>(&fs[l & 15][ko]);
#pragma unroll
        for (int nf = 0; nf < 4; ++nf) {
            bf16x8 w = *reinterpret_cast<const bf16x8*>(
                WiT + (size_t)(cb0 + wn * 64 + nf * 16 + (l & 15)) * D_ + ko);
            acc[nf] = __builtin_amdgcn_mfma_f32_16x16x32_bf16(a, w, acc[nf], 0, 0, 0);
        }
    }

    // stage gemm+bias into Cs (scatter, conflict-free by 260 stride)
#pragma unroll
    for (int nf = 0; nf < 4; ++nf) {
        const int cl = wn * 64 + nf * 16 + (l & 15);
        const float bic = bi[cb0 + cl];
#pragma unroll
        for (int r = 0; r < 4; ++r)
            Cs[(l >> 4) * 4 + r][cl] = acc[nf][r] + bic;
    }
    __syncthreads();

    // row pass: wave wn owns rows wn*4..+3, fully vectorized
    const float al = alpha_p[0];
    float* fob = fout + (size_t)b * M_ * D_;
#pragma unroll
    for (int i = 0; i < 4; ++i) {
        const int row = wn * 4 + i;
        const int m = m0 + row;
        const int mu_ = m > 0 ? m - 1 : 0;
        const int md = m < M_ - 1 ? m + 1 : M_ - 1;
        const int cl = cb0 + l * 4;
        float4 g  = *reinterpret_cast<const float4*>(&Cs[row][l * 4]);
        float4 fc = *reinterpret_cast<const float4*>(fb + (size_t)m * D_ + cl);
        float4 fu = *reinterpret_cast<const float4*>(fb + (size_t)mu_ * D_ + cl);
        float4 fd = *reinterpret_cast<const float4*>(fb + (size_t)md * D_ + cl);
        float4 o;
        o.x = fc.x + DT_ * (al * (fu.x + fd.x - 2.f * fc.x) + tanhf(g.x));
        o.y = fc.y + DT_ * (al * (fu.y + fd.y - 2.f * fc.y) + tanhf(g.y));
        o.z = fc.z + DT_ * (al * (fu.z + fd.z - 2.f * fc.z) + tanhf(g.z));
        o.w = fc.w + DT_ * (al * (fu.w + fd.w - 2.f * fc.w) + tanhf(g.w));
        *reinterpret_cast<float4*>(fob + (size_t)m * D_ + cl) = o;
    }
}

// ---------------------------------------------------------------------------
// Tail part 1: enh = LN1(lerp(field) + x) -> bf16.  Zero LDS, one wave/row.
// grid (N/4, B), 256 thr.
// ---------------------------------------------------------------------------
__global__ __launch_bounds__(256)
void k_enh(const float* __restrict__ x, const float* __restrict__ pos,
           const float* __restrict__ field, const float* __restrict__ g1,
           const float* __restrict__ b1, u16* __restrict__ enh)
{
    const int t = threadIdx.x;
    const int wid = t >> 6, l = t & 63;
    const int n = blockIdx.x * 4 + wid;
    const int b = blockIdx.y;
    const int c = l * 8;

    const float* xr = x + ((size_t)b * N_ + n) * D_ + c;
    float4 xa = *reinterpret_cast<const float4*>(xr);
    float4 xb = *reinterpret_cast<const float4*>(xr + 4);
    const float p = pos[(size_t)b * N_ + n];
    float u = p * (float)(M_ - 1);
    int i0 = (int)floorf(u);
    i0 = i0 < 0 ? 0 : (i0 > M_ - 2 ? M_ - 2 : i0);
    const float w = u - (float)i0;
    const float* fp0 = field + ((size_t)b * M_ + i0) * D_ + c;
    float4 f0a = *reinterpret_cast<const float4*>(fp0);
    float4 f0b = *reinterpret_cast<const float4*>(fp0 + 4);
    float4 f1a = *reinterpret_cast<const float4*>(fp0 + D_);
    float4 f1b = *reinterpret_cast<const float4*>(fp0 + D_ + 4);

    float s[8];
    s[0] = f0a.x + w * (f1a.x - f0a.x) + xa.x;
    s[1] = f0a.y + w * (f1a.y - f0a.y) + xa.y;
    s[2] = f0a.z + w * (f1a.z - f0a.z) + xa.z;
    s[3] = f0a.w + w * (f1a.w - f0a.w) + xa.w;
    s[4] = f0b.x + w * (f1b.x - f0b.x) + xb.x;
    s[5] = f0b.y + w * (f1b.y - f0b.y) + xb.y;
    s[6] = f0b.z + w * (f1b.z - f0b.z) + xb.z;
    s[7] = f0b.w + w * (f1b.w - f0b.w) + xb.w;

    float sum = 0.f, ss = 0.f;
#pragma unroll
    for (int j = 0; j < 8; ++j) { sum += s[j]; ss += s[j] * s[j]; }
#pragma unroll
    for (int off = 1; off <= 32; off <<= 1) {
        sum += __shfl_xor(sum, off);
        ss  += __shfl_xor(ss, off);
    }
    const float mu = sum * (1.f / 512.f);
    const float rs = rsqrtf(ss * (1.f / 512.f) - mu * mu + EPS_);

    float4 ga = *reinterpret_cast<const float4*>(g1 + c);
    float4 gb = *reinterpret_cast<const float4*>(g1 + c + 4);
    float4 ba = *reinterpret_cast<const float4*>(b1 + c);
    float4 bb = *reinterpret_cast<const float4*>(b1 + c + 4);
    u16x8 e;
    e[0] = f2bf((s[0] - mu) * rs * ga.x + ba.x);
    e[1] = f2bf((s[1] - mu) * rs * ga.y + ba.y);
    e[2] = f2bf((s[2] - mu) * rs * ga.z + ba.z);
    e[3] = f2bf((s[3] - mu) * rs * ga.w + ba.w);
    e[4] = f2bf((s[4] - mu) * rs * gb.x + bb.x);
    e[5] = f2bf((s[5] - mu) * rs * gb.y + bb.y);
    e[6] = f2bf((s[6] - mu) * rs * gb.z + bb.z);
    e[7] = f2bf((s[7] - mu) * rs * gb.w + bb.w);
    *reinterpret_cast<u16x8*>(enh + ((size_t)b * N_ + n) * D_ + c) = e;
}

// ---------------------------------------------------------------------------
// Tail part 2: out = LN2(enh @ WoT + bo + enh).
// m97-style: per-K-step LDS staging of A(64x64) and B(512x64) via
// global_load_lds w16 with chunk^(row&7) source-pre-swizzle.
// grid (B*N/64), 512 thr (8 waves 2x4). Dynamic LDS 72KB (Cs reuses it).
// ---------------------------------------------------------------------------
__global__ __launch_bounds__(512, 4)
void k_gemm_ln(const u16* __restrict__ enh, const u16* __restrict__ WoT,
               const float* __restrict__ bo, const float* __restrict__ g2,
               const float* __restrict__ b2, float* __restrict__ out)
{
    extern __shared__ u16 smem[];            // 72 KB
    u16* As = smem;                          // [64][64] linear+src-swz (8 KB)
    u16* Bs = smem + 64 * 64;                // [512][64] linear+src-swz (64 KB)
    float* Cs = (float*)smem;                // [32][516] fp32, reused post-GEMM

    const int t = threadIdx.x;
    const int r0 = blockIdx.x * 64;          // row in flattened [B*N][D]
    const int l = t & 63, wid = t >> 6;
    const int wm = wid >> 2, wn = wid & 3;

    f32x4 acc[2][8];
#pragma unroll
    for (int i = 0; i < 2; ++i)
#pragma unroll
        for (int j = 0; j < 8; ++j) acc[i][j] = (f32x4){0.f, 0.f, 0.f, 0.f};

    // staging assignments (chunk = 8 bf16 = 16B)
    const int a_row = t >> 3, a_sch = t & 7;                  // A: 512 chunks
    const u16* a_src = enh + (size_t)(r0 + a_row) * D_ + (a_sch ^ (a_row & 7)) * 8;
    u16* a_dst = As + (size_t)(wid * 64) * 8;                 // wave-uniform base

    const int fr = l & 15, fj = l >> 4;                       // frag coords

    for (int ks = 0; ks < 8; ++ks) {
        const int kk = ks * 64;
        __syncthreads();                     // prev compute done (tiles reusable)
        gload16(a_src + kk, a_dst);
#pragma unroll
        for (int i = 0; i < 8; ++i) {
            const int cid = t + i * 512;                      // B chunk id
            const int brow = cid >> 3, bsch = cid & 7;
            gload16(WoT + (size_t)brow * D_ + kk + ((bsch ^ (brow & 7)) * 8),
                    Bs + (size_t)(wid * 64 + i * 512) * 8);
        }
        __syncthreads();                     // loads landed (vmcnt0 at barrier)

#pragma unroll
        for (int kl = 0; kl < 2; ++kl) {     // two k-halves of 32
            const int cbase = kl * 4 + fj;   // chunk index 0..7
            const int ar0 = wm * 32 + fr, ar1 = ar0 + 16;
            bf16x8 a0 = *reinterpret_cast<const bf16x8*>(
                As + ar0 * 64 + ((cbase ^ (ar0 & 7)) * 8));
            bf16x8 a1 = *reinterpret_cast<const bf16x8*>(
                As + ar1 * 64 + ((cbase ^ (ar1 & 7)) * 8));
#pragma unroll
            for (int nf = 0; nf < 8; ++nf) {
                const int bcol = wn * 128 + nf * 16 + fr;
                bf16x8 bw = *reinterpret_cast<const bf16x8*>(
                    Bs + bcol * 64 + ((cbase ^ (bcol & 7)) * 8));
                acc[0][nf] = __builtin_amdgcn_mfma_f32_16x16x32_bf16(a0, bw, acc[0][nf], 0, 0, 0);
                acc[1][nf] = __builtin_amdgcn_mfma_f32_16x16x32_bf16(a1, bw, acc[1][nf], 0, 0, 0);
            }
        }
    }

#pragma unroll
    for (int mf = 0; mf < 2; ++mf) {
        __syncthreads();   // pass separation (protects Cs reuse vs B reads / prev pass)
        // scatter acc + bias into Cs; localrow = wm*16 + (l>>4)*4 + r
#pragma unroll
        for (int nf = 0; nf < 8; ++nf) {
            const int col = wn * 128 + nf * 16 + fr;
            const float boc = bo[col];
#pragma unroll
            for (int r = 0; r < 4; ++r)
                Cs[(wm * 16 + fj * 4 + r) * 516 + col] = acc[mf][nf][r] + boc;
        }
        __syncthreads();
        // row pass: wave wid owns localrows wid*4..+3; cols {l*4, 256+l*4}
#pragma unroll
        for (int i = 0; i < 4; ++i) {
            const int lr = wid * 4 + i;
            const int grow = r0 + (lr >> 4) * 32 + mf * 16 + (lr & 15);
            const int c1 = l * 4, c2 = 256 + l * 4;
            float4 fa = *reinterpret_cast<const float4*>(&Cs[lr * 516 + c1]);
            float4 fb4 = *reinterpret_cast<const float4*>(&Cs[lr * 516 + c2]);
            u16x4 e1 = *reinterpret_cast<const u16x4*>(enh + (size_t)grow * D_ + c1);
            u16x4 e2 = *reinterpret_cast<const u16x4*>(enh + (size_t)grow * D_ + c2);
            float v[8];
            v[0] = fa.x + bf2f(e1[0]); v[1] = fa.y + bf2f(e1[1]);
            v[2] = fa.z + bf2f(e1[2]); v[3] = fa.w + bf2f(e1[3]);
            v[4] = fb4.x + bf2f(e2[0]); v[5] = fb4.y + bf2f(e2[1]);
            v[6] = fb4.z + bf2f(e2[2]); v[7] = fb4.w + bf2f(e2[3]);

            float sum = 0.f, ss = 0.f;
#pragma unroll
            for (int j = 0; j < 8; ++j) { sum += v[j]; ss += v[j] * v[j]; }
#pragma unroll
            for (int off = 1; off <= 32; off <<= 1) {
                sum += __shfl_xor(sum, off);
                ss  += __shfl_xor(ss, off);
            }
            const float mu = sum * (1.f / 512.f);
            const float rs = rsqrtf(ss * (1.f / 512.f) - mu * mu + EPS_);

            float4 ga = *reinterpret_cast<const float4*>(g2 + c1);
            float4 gb = *reinterpret_cast<const float4*>(g2 + c2);
            float4 ba = *reinterpret_cast<const float4*>(b2 + c1);
            float4 bb = *reinterpret_cast<const float4*>(b2 + c2);
            float4 oa, ob;
            oa.x = (v[0] - mu) * rs * ga.x + ba.x;
            oa.y = (v[1] - mu) * rs * ga.y + ba.y;
            oa.z = (v[2] - mu) * rs * ga.z + ba.z;
            oa.w = (v[3] - mu) * rs * ga.w + ba.w;
            ob.x = (v[4] - mu) * rs * gb.x + bb.x;
            ob.y = (v[5] - mu) * rs * gb.y + bb.y;
            ob.z = (v[6] - mu) * rs * gb.z + bb.z;
            ob.w = (v[7] - mu) * rs * gb.w + bb.w;
            float* orow = out + (size_t)grow * D_;
            *reinterpret_cast<float4*>(orow + c1) = oa;
            *reinterpret_cast<float4*>(orow + c2) = ob;
        }
    }
}

extern "C" void kernel_launch(void* const* d_in, const int* in_sizes, int n_in,
                              void* d_out, int out_size, void* d_ws, size_t ws_size,
                              hipStream_t stream) {
    (void)in_sizes; (void)n_in; (void)out_size; (void)ws_size;
    const float* x   = (const float*)d_in[0];
    const float* pos = (const float*)d_in[1];
    const float* gp  = (const float*)d_in[2];
    const float* ls  = (const float*)d_in[3];
    const float* al  = (const float*)d_in[4];
    const float* Wi  = (const float*)d_in[5];
    const float* bi  = (const float*)d_in[6];
    const float* g1  = (const float*)d_in[7];
    const float* b1  = (const float*)d_in[8];
    const float* Wo  = (const float*)d_in[9];
    const float* bo  = (const float*)d_in[10];
    const float* g2  = (const float*)d_in[11];
    const float* b2  = (const float*)d_in[12];
    float* out = (float*)d_out;

    float* f0 = (float*)d_ws;                              // 8 MB fp32 field
    float* f1 = f0 + (size_t)B_ * M_ * D_;                 // 8 MB ping-pong
    u16* xT  = (u16*)(f1 + (size_t)B_ * M_ * D_);          // 32 MB bf16 x^T
    u16* WiT = xT + (size_t)B_ * D_ * N_;                  // 512 KB
    u16* WoT = WiT + (size_t)D_ * D_;                      // 512 KB
    u16* enh = xT;                                         // alias: xT dead after project
    u16* kern = (u16*)d_out;                               // 32 MB scratch in d_out
                                                           // (dead before k_gemm_ln writes)

    const int smBytes = 64 * 64 * 2 + 512 * 64 * 2;        // 73728 B dynamic LDS
    hipFuncSetAttribute(reinterpret_cast<const void*>(k_gemm_ln),
                        hipFuncAttributeMaxDynamicSharedMemorySize, smBytes);
    hipFuncSetAttribute(reinterpret_cast<const void*>(k_projgemm),
                        hipFuncAttributeMaxDynamicSharedMemorySize, smBytes);

    hipMemsetAsync(f0, 0, (size_t)B_ * M_ * D_ * sizeof(float), stream);
    k_kern<<<dim3(M_ / 8, B_), 256, 0, stream>>>(pos, gp, ls, kern);
    k_prep_T<<<dim3(D_ / 64, N_ / 64, B_), 256, 0, stream>>>(x, xT, N_, D_);
    k_prep_T<<<dim3(D_ / 64, D_ / 64, 1), 256, 0, stream>>>(Wi, WiT, D_, D_);
    k_prep_T<<<dim3(D_ / 64, D_ / 64, 1), 256, 0, stream>>>(Wo, WoT, D_, D_);
    k_projgemm<<<dim3(256), 512, smBytes, stream>>>(kern, xT, f0);
    k_diffuse<<<dim3(M_ / 16, D_ / 256, B_), 256, 0, stream>>>(f0, WiT, bi, al, f1);
    k_diffuse<<<dim3(M_ / 16, D_ / 256, B_), 256, 0, stream>>>(f1, WiT, bi, al, f0);
    k_diffuse<<<dim3(M_ / 16, D_ / 256, B_), 256, 0, stream>>>(f0, WiT, bi, al, f1);
    k_diffuse<<<dim3(M_ / 16, D_ / 256, B_), 256, 0, stream>>>(f1, WiT, bi, al, f0);
    k_enh<<<dim3(N_ / 4, B_), 256, 0, stream>>>(x, pos, f0, g1, b1, enh);
    k_gemm_ln<<<dim3(B_ * N_ / 64), 512, smBytes, stream>>>(enh, WoT, bo, g2, b2, out);
}

// Round 8
// 223.405 us; speedup vs baseline: 1.3496x; 1.0371x over previous
//
#include <hip/hip_runtime.h>
#include <cmath>

#define B_ 8
#define N_ 4096
#define D_ 512
#define M_ 512
#define EPS_ 1e-5f
#define DT_ 0.25f

typedef unsigned short u16;
typedef unsigned int u32;
typedef __attribute__((ext_vector_type(8))) u16 u16x8;
typedef __attribute__((ext_vector_type(4))) u16 u16x4;
typedef __attribute__((ext_vector_type(8))) short bf16x8;
typedef __attribute__((ext_vector_type(4))) float f32x4;

__device__ __forceinline__ u16 f2bf(float f) {
    u32 u = __builtin_bit_cast(u32, f);
    u32 r = u + 0x7fffu + ((u >> 16) & 1u);   // round-to-nearest-even
    return (u16)(r >> 16);
}
__device__ __forceinline__ float bf2f(u16 h) {
    return __builtin_bit_cast(float, (u32)h << 16);
}

// async global->LDS, 16B per lane; lds must be wave-uniform base (+lane*16 HW)
__device__ __forceinline__ void gload16(const void* g, void* l) {
    __builtin_amdgcn_global_load_lds(
        (const __attribute__((address_space(1))) void*)g,
        (__attribute__((address_space(3))) void*)l, 16, 0, 0);
}

// ---------------------------------------------------------------------------
// Transpose + fp32->bf16: src [Z][R][C] -> dst [Z][C][R]
// ---------------------------------------------------------------------------
__global__ __launch_bounds__(256)
void k_prep_T(const float* __restrict__ src, u16* __restrict__ dst, int R, int C)
{
    __shared__ float tile[64][65];
    const int t = threadIdx.x;
    const int c0 = blockIdx.x * 64;
    const int r0 = blockIdx.y * 64;
    const int z  = blockIdx.z;
    const float* s = src + (size_t)z * R * C;
    u16* d = dst + (size_t)z * R * C;
    const int rl = t >> 4, cc = (t & 15) * 4;
#pragma unroll
    for (int i = 0; i < 4; ++i) {
        float4 v = *reinterpret_cast<const float4*>(s + (size_t)(r0 + rl + i * 16) * C + c0 + cc);
        tile[rl + i * 16][cc + 0] = v.x;
        tile[rl + i * 16][cc + 1] = v.y;
        tile[rl + i * 16][cc + 2] = v.z;
        tile[rl + i * 16][cc + 3] = v.w;
    }
    __syncthreads();
#pragma unroll
    for (int i = 0; i < 2; ++i) {
        int q = t + i * 256;
        int cl = q >> 3, rc = (q & 7) * 8;
        u16x8 o;
#pragma unroll
        for (int j = 0; j < 8; ++j) o[j] = f2bf(tile[rc + j][cl]);
        *reinterpret_cast<u16x8*>(d + (size_t)(c0 + cl) * R + r0 + rc) = o;
    }
}

// ---------------------------------------------------------------------------
// RBF kernel matrix: kern[b][m][n] = exp(-(g_m - p_n)^2 / (2 sigma^2)) bf16.
// grid (M/8, B), 256 thr. Thread owns 16 n-cols for 8 m-rows. Coalesced.
// ---------------------------------------------------------------------------
__global__ __launch_bounds__(256)
void k_kern(const float* __restrict__ pos, const float* __restrict__ gp,
            const float* __restrict__ log_sigma, u16* __restrict__ kern)
{
    const int t = threadIdx.x;
    const int m0 = blockIdx.x * 8;
    const int b  = blockIdx.y;
    const int n0 = t * 16;

    const float sigma = __expf(log_sigma[0]);
    const float ninv2s2 = -0.5f / (sigma * sigma);

    const float* pb = pos + (size_t)b * N_ + n0;
    float4 p0 = *reinterpret_cast<const float4*>(pb);
    float4 p1 = *reinterpret_cast<const float4*>(pb + 4);
    float4 p2 = *reinterpret_cast<const float4*>(pb + 8);
    float4 p3 = *reinterpret_cast<const float4*>(pb + 12);
    float pv[16] = {p0.x, p0.y, p0.z, p0.w, p1.x, p1.y, p1.z, p1.w,
                    p2.x, p2.y, p2.z, p2.w, p3.x, p3.y, p3.z, p3.w};

#pragma unroll
    for (int mi = 0; mi < 8; ++mi) {
        const float gm = gp[(size_t)b * M_ + m0 + mi];
        u16x8 k0, k1;
#pragma unroll
        for (int j = 0; j < 8; ++j) {
            float d = gm - pv[j];
            k0[j] = f2bf(__expf(d * d * ninv2s2));
        }
#pragma unroll
        for (int j = 0; j < 8; ++j) {
            float d = gm - pv[j + 8];
            k1[j] = f2bf(__expf(d * d * ninv2s2));
        }
        u16* dst = kern + ((size_t)(b * M_ + m0 + mi)) * N_ + n0;
        *reinterpret_cast<u16x8*>(dst)     = k0;
        *reinterpret_cast<u16x8*>(dst + 8) = k1;
    }
}

// ---------------------------------------------------------------------------
// Projection GEMM: field[b][64 m][256 n-cols] += kern-chunk @ xT-chunk.
// Tile 64x256, 40KB LDS -> 2 blocks/CU (barrier-stall hiding via co-resident
// block, m97/m114 mechanism). 512 blocks, XCD-grouped: the 16 blocks
// (8 mtiles x 2 ntiles) sharing one (b,chunk) xT slab land on one XCD.
// 512 thr (8 waves 2x4), global_load_lds w16, chunk^(row&7) src-pre-swizzle.
// Cross-chunk accumulation via coalesced unsafeAtomicAdd.
// ---------------------------------------------------------------------------
__global__ __launch_bounds__(512, 4)
void k_projgemm(const u16* __restrict__ kern, const u16* __restrict__ xT,
                float* __restrict__ field)
{
    extern __shared__ u16 smem[];            // 40 KB
    u16* As = smem;                          // [64][64] kern rows (8 KB)
    u16* Bs = smem + 64 * 64;                // [256][64] xT rows (32 KB)

    const int t = threadIdx.x;
    // XCD-aware decode: all 16 blocks of a (b,chunk) group share d%8.
    const int d = blockIdx.x;                // 0..511
    const int xcd = d & 7;
    const int q = d >> 3;                    // 0..63
    const int w = q & 15;                    // within-group: mtile + ntile
    const int mtile = w & 7;
    const int ntile = w >> 3;                // 0..1
    const int gq = q >> 4;                   // 0..3
    const int g = gq * 8 + xcd;              // group id 0..31
    const int b = g & 7;
    const int m0 = mtile * 64;
    const int cb0 = ntile * 256;             // output col base
    const int nc0 = (g >> 3) * 1024;         // n-chunk base

    const int l = t & 63, wid = t >> 6;
    const int wm = wid >> 2, wn = wid & 3;

    f32x4 acc[2][4];
#pragma unroll
    for (int i = 0; i < 2; ++i)
#pragma unroll
        for (int j = 0; j < 4; ++j) acc[i][j] = (f32x4){0.f, 0.f, 0.f, 0.f};

    // staging assignments (chunk = 8 bf16 = 16B)
    const int a_row = t >> 3, a_sch = t & 7;
    const u16* a_src = kern + ((size_t)(b * M_ + m0 + a_row)) * N_ + nc0
                            + (a_sch ^ (a_row & 7)) * 8;
    u16* a_dst = As + (size_t)wid * 512;          // wave-uniform base
    const u16* xb = xT + ((size_t)b * D_ + cb0) * N_ + nc0;

    const int fr = l & 15, fj = l >> 4;

    for (int ks = 0; ks < 16; ++ks) {
        const int kk = ks * 64;
        __syncthreads();                     // prev compute done
        gload16(a_src + kk, a_dst);
#pragma unroll
        for (int i = 0; i < 4; ++i) {
            const int cid = t + i * 512;
            const int brow = cid >> 3, bsch = cid & 7;
            gload16(xb + (size_t)brow * N_ + kk + ((bsch ^ (brow & 7)) * 8),
                    Bs + (size_t)wid * 512 + i * 4096);
        }
        __syncthreads();                     // loads landed

#pragma unroll
        for (int kl = 0; kl < 2; ++kl) {
            const int cbase = kl * 4 + fj;
            const int ar0 = wm * 32 + fr, ar1 = ar0 + 16;
            bf16x8 a0 = *reinterpret_cast<const bf16x8*>(
                As + ar0 * 64 + ((cbase ^ (ar0 & 7)) * 8));
            bf16x8 a1 = *reinterpret_cast<const bf16x8*>(
                As + ar1 * 64 + ((cbase ^ (ar1 & 7)) * 8));
#pragma unroll
            for (int nf = 0; nf < 4; ++nf) {
                const int bcol = wn * 64 + nf * 16 + fr;
                bf16x8 bw = *reinterpret_cast<const bf16x8*>(
                    Bs + bcol * 64 + ((cbase ^ (bcol & 7)) * 8));
                acc[0][nf] = __builtin_amdgcn_mfma_f32_16x16x32_bf16(a0, bw, acc[0][nf], 0, 0, 0);
                acc[1][nf] = __builtin_amdgcn_mfma_f32_16x16x32_bf16(a1, bw, acc[1][nf], 0, 0, 0);
            }
        }
    }

    float* fb = field + (size_t)b * M_ * D_;
#pragma unroll
    for (int mf = 0; mf < 2; ++mf)
#pragma unroll
        for (int nf = 0; nf < 4; ++nf) {
            const int col = cb0 + wn * 64 + nf * 16 + fr;
#pragma unroll
            for (int r = 0; r < 4; ++r) {
                const int m = m0 + wm * 32 + mf * 16 + fj * 4 + r;
                unsafeAtomicAdd(fb + (size_t)m * D_ + col, acc[mf][nf][r]);
            }
        }
}

// ---------------------------------------------------------------------------
// Diffusion step: fout = fin + dt*(alpha*lap + tanh(fin @ Wi + bi))
// grid (M/16, D/256, B), 256 thr. GEMM -> Cs stage -> coalesced row pass.
// ---------------------------------------------------------------------------
__global__ __launch_bounds__(256)
void k_diffuse(const float* __restrict__ fin, const u16* __restrict__ WiT,
               const float* __restrict__ bi, const float* __restrict__ alpha_p,
               float* __restrict__ fout)
{
    __shared__ u16 fs[16][520];      // 16.6 KB bf16 field rows
    __shared__ float Cs[16][260];    // 16.6 KB fp32 gemm stage (260: conflict-free)
    const int t = threadIdx.x;
    const int m0 = blockIdx.x * 16;
    const int cb0 = blockIdx.y * 256;
    const int b = blockIdx.z;
    const int l = t & 63, wn = t >> 6;
    const float* fb = fin + (size_t)b * M_ * D_;

    {
        const int row = t >> 4, ch = (t & 15) * 32;
        const float* src = fb + (size_t)(m0 + row) * D_ + ch;
#pragma unroll
        for (int j = 0; j < 4; ++j) {
            float4 v0 = *reinterpret_cast<const float4*>(src + j * 8);
            float4 v1 = *reinterpret_cast<const float4*>(src + j * 8 + 4);
            u16x8 o;
            o[0] = f2bf(v0.x); o[1] = f2bf(v0.y); o[2] = f2bf(v0.z); o[3] = f2bf(v0.w);
            o[4] = f2bf(v1.x); o[5] = f2bf(v1.y); o[6] = f2bf(v1.z); o[7] = f2bf(v1.w);
            *reinterpret_cast<u16x8*>(&fs[row][ch + j * 8]) = o;
        }
    }
    __syncthreads();

    f32x4 acc[4];
#pragma unroll
    for (int i = 0; i < 4; ++i) acc[i] = (f32x4){0.f, 0.f, 0.f, 0.f};

    for (int kk = 0; kk < D_; kk += 32) {
        const int ko = kk + (l >> 4) * 8;
        bf16x8 a = *reinterpret_cast<const bf16x8*>(&fs[l & 15][ko]);
#pragma unroll
        for (int nf = 0; nf < 4; ++nf) {
            bf16x8 w = *reinterpret_cast<const bf16x8*>(
                WiT + (size_t)(cb0 + wn * 64 + nf * 16 + (l & 15)) * D_ + ko);
            acc[nf] = __builtin_amdgcn_mfma_f32_16x16x32_bf16(a, w, acc[nf], 0, 0, 0);
        }
    }

    // stage gemm+bias into Cs (scatter, conflict-free by 260 stride)
#pragma unroll
    for (int nf = 0; nf < 4; ++nf) {
        const int cl = wn * 64 + nf * 16 + (l & 15);
        const float bic = bi[cb0 + cl];
#pragma unroll
        for (int r = 0; r < 4; ++r)
            Cs[(l >> 4) * 4 + r][cl] = acc[nf][r] + bic;
    }
    __syncthreads();

    // row pass: wave wn owns rows wn*4..+3, fully vectorized
    const float al = alpha_p[0];
    float* fob = fout + (size_t)b * M_ * D_;
#pragma unroll
    for (int i = 0; i < 4; ++i) {
        const int row = wn * 4 + i;
        const int m = m0 + row;
        const int mu_ = m > 0 ? m - 1 : 0;
        const int md = m < M_ - 1 ? m + 1 : M_ - 1;
        const int cl = cb0 + l * 4;
        float4 g  = *reinterpret_cast<const float4*>(&Cs[row][l * 4]);
        float4 fc = *reinterpret_cast<const float4*>(fb + (size_t)m * D_ + cl);
        float4 fu = *reinterpret_cast<const float4*>(fb + (size_t)mu_ * D_ + cl);
        float4 fd = *reinterpret_cast<const float4*>(fb + (size_t)md * D_ + cl);
        float4 o;
        o.x = fc.x + DT_ * (al * (fu.x + fd.x - 2.f * fc.x) + tanhf(g.x));
        o.y = fc.y + DT_ * (al * (fu.y + fd.y - 2.f * fc.y) + tanhf(g.y));
        o.z = fc.z + DT_ * (al * (fu.z + fd.z - 2.f * fc.z) + tanhf(g.z));
        o.w = fc.w + DT_ * (al * (fu.w + fd.w - 2.f * fc.w) + tanhf(g.w));
        *reinterpret_cast<float4*>(fob + (size_t)m * D_ + cl) = o;
    }
}

// ---------------------------------------------------------------------------
// Tail part 1: enh = LN1(lerp(field) + x) -> bf16.  Zero LDS, one wave/row.
// grid (N/4, B), 256 thr.
// ---------------------------------------------------------------------------
__global__ __launch_bounds__(256)
void k_enh(const float* __restrict__ x, const float* __restrict__ pos,
           const float* __restrict__ field, const float* __restrict__ g1,
           const float* __restrict__ b1, u16* __restrict__ enh)
{
    const int t = threadIdx.x;
    const int wid = t >> 6, l = t & 63;
    const int n = blockIdx.x * 4 + wid;
    const int b = blockIdx.y;
    const int c = l * 8;

    const float* xr = x + ((size_t)b * N_ + n) * D_ + c;
    float4 xa = *reinterpret_cast<const float4*>(xr);
    float4 xb = *reinterpret_cast<const float4*>(xr + 4);
    const float p = pos[(size_t)b * N_ + n];
    float u = p * (float)(M_ - 1);
    int i0 = (int)floorf(u);
    i0 = i0 < 0 ? 0 : (i0 > M_ - 2 ? M_ - 2 : i0);
    const float w = u - (float)i0;
    const float* fp0 = field + ((size_t)b * M_ + i0) * D_ + c;
    float4 f0a = *reinterpret_cast<const float4*>(fp0);
    float4 f0b = *reinterpret_cast<const float4*>(fp0 + 4);
    float4 f1a = *reinterpret_cast<const float4*>(fp0 + D_);
    float4 f1b = *reinterpret_cast<const float4*>(fp0 + D_ + 4);

    float s[8];
    s[0] = f0a.x + w * (f1a.x - f0a.x) + xa.x;
    s[1] = f0a.y + w * (f1a.y - f0a.y) + xa.y;
    s[2] = f0a.z + w * (f1a.z - f0a.z) + xa.z;
    s[3] = f0a.w + w * (f1a.w - f0a.w) + xa.w;
    s[4] = f0b.x + w * (f1b.x - f0b.x) + xb.x;
    s[5] = f0b.y + w * (f1b.y - f0b.y) + xb.y;
    s[6] = f0b.z + w * (f1b.z - f0b.z) + xb.z;
    s[7] = f0b.w + w * (f1b.w - f0b.w) + xb.w;

    float sum = 0.f, ss = 0.f;
#pragma unroll
    for (int j = 0; j < 8; ++j) { sum += s[j]; ss += s[j] * s[j]; }
#pragma unroll
    for (int off = 1; off <= 32; off <<= 1) {
        sum += __shfl_xor(sum, off);
        ss  += __shfl_xor(ss, off);
    }
    const float mu = sum * (1.f / 512.f);
    const float rs = rsqrtf(ss * (1.f / 512.f) - mu * mu + EPS_);

    float4 ga = *reinterpret_cast<const float4*>(g1 + c);
    float4 gb = *reinterpret_cast<const float4*>(g1 + c + 4);
    float4 ba = *reinterpret_cast<const float4*>(b1 + c);
    float4 bb = *reinterpret_cast<const float4*>(b1 + c + 4);
    u16x8 e;
    e[0] = f2bf((s[0] - mu) * rs * ga.x + ba.x);
    e[1] = f2bf((s[1] - mu) * rs * ga.y + ba.y);
    e[2] = f2bf((s[2] - mu) * rs * ga.z + ba.z);
    e[3] = f2bf((s[3] - mu) * rs * ga.w + ba.w);
    e[4] = f2bf((s[4] - mu) * rs * gb.x + bb.x);
    e[5] = f2bf((s[5] - mu) * rs * gb.y + bb.y);
    e[6] = f2bf((s[6] - mu) * rs * gb.z + bb.z);
    e[7] = f2bf((s[7] - mu) * rs * gb.w + bb.w);
    *reinterpret_cast<u16x8*>(enh + ((size_t)b * N_ + n) * D_ + c) = e;
}

// ---------------------------------------------------------------------------
// Tail part 2: out = LN2(enh @ WoT + bo + enh).
// m97-style: per-K-step LDS staging of A(64x64) and B(512x64) via
// global_load_lds w16 with chunk^(row&7) source-pre-swizzle.
// grid (B*N/64), 512 thr (8 waves 2x4). Dynamic LDS 72KB (Cs reuses it).
// ---------------------------------------------------------------------------
__global__ __launch_bounds__(512, 4)
void k_gemm_ln(const u16* __restrict__ enh, const u16* __restrict__ WoT,
               const float* __restrict__ bo, const float* __restrict__ g2,
               const float* __restrict__ b2, float* __restrict__ out)
{
    extern __shared__ u16 smem[];            // 72 KB
    u16* As = smem;                          // [64][64] linear+src-swz (8 KB)
    u16* Bs = smem + 64 * 64;                // [512][64] linear+src-swz (64 KB)
    float* Cs = (float*)smem;                // [32][516] fp32, reused post-GEMM

    const int t = threadIdx.x;
    const int r0 = blockIdx.x * 64;          // row in flattened [B*N][D]
    const int l = t & 63, wid = t >> 6;
    const int wm = wid >> 2, wn = wid & 3;

    f32x4 acc[2][8];
#pragma unroll
    for (int i = 0; i < 2; ++i)
#pragma unroll
        for (int j = 0; j < 8; ++j) acc[i][j] = (f32x4){0.f, 0.f, 0.f, 0.f};

    // staging assignments (chunk = 8 bf16 = 16B)
    const int a_row = t >> 3, a_sch = t & 7;                  // A: 512 chunks
    const u16* a_src = enh + (size_t)(r0 + a_row) * D_ + (a_sch ^ (a_row & 7)) * 8;
    u16* a_dst = As + (size_t)wid * 512;                      // wave-uniform base

    const int fr = l & 15, fj = l >> 4;                       // frag coords

    for (int ks = 0; ks < 8; ++ks) {
        const int kk = ks * 64;
        __syncthreads();                     // prev compute done (tiles reusable)
        gload16(a_src + kk, a_dst);
#pragma unroll
        for (int i = 0; i < 8; ++i) {
            const int cid = t + i * 512;                      // B chunk id
            const int brow = cid >> 3, bsch = cid & 7;
            gload16(WoT + (size_t)brow * D_ + kk + ((bsch ^ (brow & 7)) * 8),
                    Bs + (size_t)wid * 512 + i * 4096);
        }
        __syncthreads();                     // loads landed (vmcnt0 at barrier)

#pragma unroll
        for (int kl = 0; kl < 2; ++kl) {     // two k-halves of 32
            const int cbase = kl * 4 + fj;   // chunk index 0..7
            const int ar0 = wm * 32 + fr, ar1 = ar0 + 16;
            bf16x8 a0 = *reinterpret_cast<const bf16x8*>(
                As + ar0 * 64 + ((cbase ^ (ar0 & 7)) * 8));
            bf16x8 a1 = *reinterpret_cast<const bf16x8*>(
                As + ar1 * 64 + ((cbase ^ (ar1 & 7)) * 8));
#pragma unroll
            for (int nf = 0; nf < 8; ++nf) {
                const int bcol = wn * 128 + nf * 16 + fr;
                bf16x8 bw = *reinterpret_cast<const bf16x8*>(
                    Bs + bcol * 64 + ((cbase ^ (bcol & 7)) * 8));
                acc[0][nf] = __builtin_amdgcn_mfma_f32_16x16x32_bf16(a0, bw, acc[0][nf], 0, 0, 0);
                acc[1][nf] = __builtin_amdgcn_mfma_f32_16x16x32_bf16(a1, bw, acc[1][nf], 0, 0, 0);
            }
        }
    }

#pragma unroll
    for (int mf = 0; mf < 2; ++mf) {
        __syncthreads();   // pass separation (protects Cs reuse vs B reads / prev pass)
        // scatter acc + bias into Cs; localrow = wm*16 + (l>>4)*4 + r
#pragma unroll
        for (int nf = 0; nf < 8; ++nf) {
            const int col = wn * 128 + nf * 16 + fr;
            const float boc = bo[col];
#pragma unroll
            for (int r = 0; r < 4; ++r)
                Cs[(wm * 16 + fj * 4 + r) * 516 + col] = acc[mf][nf][r] + boc;
        }
        __syncthreads();
        // row pass: wave wid owns localrows wid*4..+3; cols {l*4, 256+l*4}
#pragma unroll
        for (int i = 0; i < 4; ++i) {
            const int lr = wid * 4 + i;
            const int grow = r0 + (lr >> 4) * 32 + mf * 16 + (lr & 15);
            const int c1 = l * 4, c2 = 256 + l * 4;
            float4 fa = *reinterpret_cast<const float4*>(&Cs[lr * 516 + c1]);
            float4 fb4 = *reinterpret_cast<const float4*>(&Cs[lr * 516 + c2]);
            u16x4 e1 = *reinterpret_cast<const u16x4*>(enh + (size_t)grow * D_ + c1);
            u16x4 e2 = *reinterpret_cast<const u16x4*>(enh + (size_t)grow * D_ + c2);
            float v[8];
            v[0] = fa.x + bf2f(e1[0]); v[1] = fa.y + bf2f(e1[1]);
            v[2] = fa.z + bf2f(e1[2]); v[3] = fa.w + bf2f(e1[3]);
            v[4] = fb4.x + bf2f(e2[0]); v[5] = fb4.y + bf2f(e2[1]);
            v[6] = fb4.z + bf2f(e2[2]); v[7] = fb4.w + bf2f(e2[3]);

            float sum = 0.f, ss = 0.f;
#pragma unroll
            for (int j = 0; j < 8; ++j) { sum += v[j]; ss += v[j] * v[j]; }
#pragma unroll
            for (int off = 1; off <= 32; off <<= 1) {
                sum += __shfl_xor(sum, off);
                ss  += __shfl_xor(ss, off);
            }
            const float mu = sum * (1.f / 512.f);
            const float rs = rsqrtf(ss * (1.f / 512.f) - mu * mu + EPS_);

            float4 ga = *reinterpret_cast<const float4*>(g2 + c1);
            float4 gb = *reinterpret_cast<const float4*>(g2 + c2);
            float4 ba = *reinterpret_cast<const float4*>(b2 + c1);
            float4 bb = *reinterpret_cast<const float4*>(b2 + c2);
            float4 oa, ob;
            oa.x = (v[0] - mu) * rs * ga.x + ba.x;
            oa.y = (v[1] - mu) * rs * ga.y + ba.y;
            oa.z = (v[2] - mu) * rs * ga.z + ba.z;
            oa.w = (v[3] - mu) * rs * ga.w + ba.w;
            ob.x = (v[4] - mu) * rs * gb.x + bb.x;
            ob.y = (v[5] - mu) * rs * gb.y + bb.y;
            ob.z = (v[6] - mu) * rs * gb.z + bb.z;
            ob.w = (v[7] - mu) * rs * gb.w + bb.w;
            float* orow = out + (size_t)grow * D_;
            *reinterpret_cast<float4*>(orow + c1) = oa;
            *reinterpret_cast<float4*>(orow + c2) = ob;
        }
    }
}

extern "C" void kernel_launch(void* const* d_in, const int* in_sizes, int n_in,
                              void* d_out, int out_size, void* d_ws, size_t ws_size,
                              hipStream_t stream) {
    (void)in_sizes; (void)n_in; (void)out_size; (void)ws_size;
    const float* x   = (const float*)d_in[0];
    const float* pos = (const float*)d_in[1];
    const float* gp  = (const float*)d_in[2];
    const float* ls  = (const float*)d_in[3];
    const float* al  = (const float*)d_in[4];
    const float* Wi  = (const float*)d_in[5];
    const float* bi  = (const float*)d_in[6];
    const float* g1  = (const float*)d_in[7];
    const float* b1  = (const float*)d_in[8];
    const float* Wo  = (const float*)d_in[9];
    const float* bo  = (const float*)d_in[10];
    const float* g2  = (const float*)d_in[11];
    const float* b2  = (const float*)d_in[12];
    float* out = (float*)d_out;

    float* f0 = (float*)d_ws;                              // 8 MB fp32 field
    float* f1 = f0 + (size_t)B_ * M_ * D_;                 // 8 MB ping-pong
    u16* xT  = (u16*)(f1 + (size_t)B_ * M_ * D_);          // 32 MB bf16 x^T
    u16* WiT = xT + (size_t)B_ * D_ * N_;                  // 512 KB
    u16* WoT = WiT + (size_t)D_ * D_;                      // 512 KB
    u16* enh = xT;                                         // alias: xT dead after project
    u16* kern = (u16*)d_out;                               // 32 MB scratch in d_out
                                                           // (dead before k_gemm_ln writes)

    const int smGemm = 64 * 64 * 2 + 512 * 64 * 2;         // 73728 B (k_gemm_ln)
    const int smProj = 64 * 64 * 2 + 256 * 64 * 2;         // 40960 B (k_projgemm)
    hipFuncSetAttribute(reinterpret_cast<const void*>(k_gemm_ln),
                        hipFuncAttributeMaxDynamicSharedMemorySize, smGemm);
    hipFuncSetAttribute(reinterpret_cast<const void*>(k_projgemm),
                        hipFuncAttributeMaxDynamicSharedMemorySize, smProj);

    hipMemsetAsync(f0, 0, (size_t)B_ * M_ * D_ * sizeof(float), stream);
    k_kern<<<dim3(M_ / 8, B_), 256, 0, stream>>>(pos, gp, ls, kern);
    k_prep_T<<<dim3(D_ / 64, N_ / 64, B_), 256, 0, stream>>>(x, xT, N_, D_);
    k_prep_T<<<dim3(D_ / 64, D_ / 64, 1), 256, 0, stream>>>(Wi, WiT, D_, D_);
    k_prep_T<<<dim3(D_ / 64, D_ / 64, 1), 256, 0, stream>>>(Wo, WoT, D_, D_);
    k_projgemm<<<dim3(512), 512, smProj, stream>>>(kern, xT, f0);
    k_diffuse<<<dim3(M_ / 16, D_ / 256, B_), 256, 0, stream>>>(f0, WiT, bi, al, f1);
    k_diffuse<<<dim3(M_ / 16, D_ / 256, B_), 256, 0, stream>>>(f1, WiT, bi, al, f0);
    k_diffuse<<<dim3(M_ / 16, D_ / 256, B_), 256, 0, stream>>>(f0, WiT, bi, al, f1);
    k_diffuse<<<dim3(M_ / 16, D_ / 256, B_), 256, 0, stream>>>(f1, WiT, bi, al, f0);
    k_enh<<<dim3(N_ / 4, B_), 256, 0, stream>>>(x, pos, f0, g1, b1, enh);
    k_gemm_ln<<<dim3(B_ * N_ / 64), 512, smGemm, stream>>>(enh, WoT, bo, g2, b2, out);
}